// Round 10
// baseline (465.516 us; speedup 1.0000x reference)
//
#include <hip/hip_runtime.h>
#include <hip/hip_bf16.h>

#define N_NODES 200000
#define N_EDGES 800000
#define N_GRAPHS 4000
#define D_N 35
#define IN_CH 8
#define EMB 256
#define HID 128

typedef unsigned short u16;
typedef __attribute__((ext_vector_type(8))) short bf16x8;
typedef __attribute__((ext_vector_type(8))) unsigned short ushort8;
typedef __attribute__((ext_vector_type(4))) float f32x4;
typedef __attribute__((ext_vector_type(4))) unsigned uint32x4;

__device__ __forceinline__ float b2f(u16 u) {
    union { float f; unsigned v; } x; x.v = ((unsigned)u) << 16; return x.f;
}
__device__ __forceinline__ u16 f2b(float f) {
    union { float f; unsigned v; } x; x.f = f;
    unsigned r = x.v + 0x7fff + ((x.v >> 16) & 1);  // round-nearest-even
    return (u16)(r >> 16);
}
__device__ __forceinline__ void nt_store16(void* p, ushort8 v) {
    uint32x4 u;
    __builtin_memcpy(&u, &v, 16);
    __builtin_nontemporal_store(u, (uint32x4*)p);
}
#define RFL(v) __builtin_amdgcn_readfirstlane(v)

// ---------------- CSR build ----------------

__global__ void count_deg(const int* __restrict__ dst, int* __restrict__ deg, int n) {
    int e = blockIdx.x * 256 + threadIdx.x;
    if (e < n) atomicAdd(&deg[dst[e]], 1);
}

__global__ __launch_bounds__(256) void scan_a(const int* __restrict__ deg, int* __restrict__ incl1,
                                              int* __restrict__ partials, int n) {
    __shared__ int s[256];
    int tid = threadIdx.x;
    int base = blockIdx.x * 1024;
    int v[4]; int sum = 0;
#pragma unroll
    for (int j = 0; j < 4; j++) {
        int idx = base + tid * 4 + j;
        v[j] = (idx < n) ? deg[idx] : 0;
        sum += v[j];
    }
    s[tid] = sum; __syncthreads();
    for (int off = 1; off < 256; off <<= 1) {
        int t = (tid >= off) ? s[tid - off] : 0;
        __syncthreads();
        s[tid] += t;
        __syncthreads();
    }
    int run = s[tid] - sum;
#pragma unroll
    for (int j = 0; j < 4; j++) {
        int idx = base + tid * 4 + j;
        run += v[j];
        if (idx < n) incl1[idx] = run;
    }
    if (tid == 255) partials[blockIdx.x] = s[255];
}

__global__ __launch_bounds__(256) void scan_b(int* __restrict__ partials, int np) {
    __shared__ int s[256];
    int tid = threadIdx.x;
    int v = (tid < np) ? partials[tid] : 0;
    s[tid] = v; __syncthreads();
    for (int off = 1; off < 256; off <<= 1) {
        int t = (tid >= off) ? s[tid - off] : 0;
        __syncthreads();
        s[tid] += t;
        __syncthreads();
    }
    if (tid < np) partials[tid] = s[tid] - v;
}

__global__ void scan_c(int* __restrict__ rowptr, const int* __restrict__ partials, int n) {
    int i = blockIdx.x * 256 + threadIdx.x;
    if (i < n) rowptr[1 + i] += partials[i >> 10];
    if (i == 0) rowptr[0] = 0;
}

// slot-allocate by atomicSub on counts (cnt ends at 0; intra-row order nondeterministic, sum unchanged)
__global__ void fill_csr(const int* __restrict__ src, const int* __restrict__ dst,
                         const int* __restrict__ rowptr, int* __restrict__ cnt,
                         int* __restrict__ csr, int n) {
    int e = blockIdx.x * 256 + threadIdx.x;
    if (e >= n) return;
    int d = dst[e];
    int p = atomicSub(&cnt[d], 1) - 1;
    csr[rowptr[d] + p] = src[e];
}

// ---------------- weight packing ----------------

// W2/W3 [256 out][256 in] fp32 -> MFMA B-fragment order bf16 (one launch for both)
__global__ __launch_bounds__(256) void swizzle_w23(const float* __restrict__ W2, const float* __restrict__ W3,
                                                   u16* __restrict__ Wsw2, u16* __restrict__ Wsw3) {
    int t = blockIdx.x * 256 + threadIdx.x;  // 16384 threads
    const float* W = (t < 8192) ? W2 : W3;
    u16* Wsw = (t < 8192) ? Wsw2 : Wsw3;
    int tl = t & 8191;
    int lane = tl & 63;
    int n = ((tl >> 9) << 4) + (lane & 15);
    int k0 = (((tl >> 6) & 7) << 5) + ((lane >> 4) << 3);
    u16 v[8];
#pragma unroll
    for (int j = 0; j < 8; j++) v[j] = f2b(W[(size_t)n * 256 + k0 + j]);
    ushort4* o = (ushort4*)&Wsw[(size_t)tl * 8];
    o[0] = make_ushort4(v[0], v[1], v[2], v[3]);
    o[1] = make_ushort4(v[4], v[5], v[6], v[7]);
}

// W1 [256 out][8 in] -> B-fragment order for one 16x16x32 MFMA (k 8..31 zero)
__global__ __launch_bounds__(256) void swizzle_w1(const float* __restrict__ W1, u16* __restrict__ Wsw) {
    int t = blockIdx.x * 256 + threadIdx.x;  // 1024 threads: nt(16) x lane(64)
    int lane = t & 63;
    int nt = t >> 6;
    int n = nt * 16 + (lane & 15);
    int g = lane >> 4;
    u16 v[8];
#pragma unroll
    for (int j = 0; j < 8; j++) v[j] = (g == 0) ? f2b(W1[n * 8 + j]) : (u16)0;
    ushort4* o = (ushort4*)&Wsw[(size_t)t * 8];
    o[0] = make_ushort4(v[0], v[1], v[2], v[3]);
    o[1] = make_ushort4(v[4], v[5], v[6], v[7]);
}

// ---------------- emb: h0 = bf16(x @ We.T)  [N,8] ----------------
__global__ __launch_bounds__(256) void emb8(const float* __restrict__ x, const float* __restrict__ We,
                                            u16* __restrict__ h0, int n) {
    __shared__ float ws[IN_CH * D_N];
    int tid = threadIdx.x;
    for (int i = tid; i < IN_CH * D_N; i += 256) ws[i] = We[i];
    __syncthreads();
    int node = blockIdx.x * 256 + tid;
    if (node >= n) return;
    float xr[D_N];
    const float* xp = &x[(size_t)node * D_N];
#pragma unroll
    for (int k = 0; k < D_N; k++) xr[k] = xp[k];
    ushort8 o;
#pragma unroll
    for (int j = 0; j < IN_CH; j++) {
        float acc = 0.f;
#pragma unroll
        for (int k = 0; k < D_N; k++) acc += xr[k] * ws[j * D_N + k];
        o[j] = f2b(acc);
    }
    *(ushort8*)&h0[(size_t)node * IN_CH] = o;
}

// ---------------- fused layer 1: agg8 + MFMA GEMM (8->256) ----------------
__global__ __launch_bounds__(256) void fused_l1(const u16* __restrict__ h0,
                                                const int* __restrict__ rowptr,
                                                const int* __restrict__ csr,
                                                const u16* __restrict__ Wsw1,
                                                const float* __restrict__ bias,
                                                u16* __restrict__ Hout) {
    __shared__ __attribute__((aligned(16))) u16 lds[16][256];  // 8 KB; agg uses [16][8] front
    const int wid = threadIdx.x >> 6;
    const int lane = threadIdx.x & 63;
    const int row0 = blockIdx.x * 16;
    char* ldsb = (char*)lds;
    const char* h0c = (const char*)h0;

    // ---- phase 1: lane halves own 2 rows concurrently (8 slots x 4 ch-lanes) ----
    const int halfsel = lane >> 5;       // which row of the pair
    const int slot = (lane & 31) >> 2;   // edge slot 0..7
    const int cid2 = (lane & 3) * 4;     // byte offset of this lane's 2 channels
    const int rbase = row0 + wid * 4;
#pragma unroll
    for (int rp = 0; rp < 2; rp++) {
        int r = rp * 2 + halfsel;
        int er = rowptr[rbase + r];
        int tr = rowptr[rbase + r + 1];
        float2 acc = make_float2(0.f, 0.f);
        for (int eb = er; __any(eb < tr); eb += 8) {
            int e = eb + slot;
            int ce = e < tr ? e : tr - 1;
            if (ce < 0) ce = 0;
            int sidx = csr[ce];
            unsigned v = *(const unsigned*)(h0c + (size_t)sidx * 16 + cid2);
            if (e < tr) {
                union { unsigned u; float f; } lo, hi;
                lo.u = v << 16; hi.u = v & 0xffff0000u;
                acc.x += lo.f; acc.y += hi.f;
            }
        }
        acc.x += __shfl_xor(acc.x, 4, 64);  acc.y += __shfl_xor(acc.y, 4, 64);
        acc.x += __shfl_xor(acc.x, 8, 64);  acc.y += __shfl_xor(acc.y, 8, 64);
        acc.x += __shfl_xor(acc.x, 16, 64); acc.y += __shfl_xor(acc.y, 16, 64);
        if ((lane & 31) < 4) {
            unsigned pk = (unsigned)f2b(acc.x) | ((unsigned)f2b(acc.y) << 16);
            *(unsigned*)(ldsb + (wid * 4 + r) * 16 + cid2) = pk;
        }
    }
    __syncthreads();

    // ---- phase 2: A fragment (K=32: k<8 real, rest zero) ----
    const int m = lane & 15;
    const int g = lane >> 4;
    bf16x8 a = {};
    if (g == 0) a = *(const bf16x8*)(ldsb + m * 16);
    __syncthreads();

    // ---- phase 3: 1 MFMA per col-tile ----
    f32x4 acc[4];
#pragma unroll
    for (int t = 0; t < 4; t++) acc[t] = (f32x4){0.f, 0.f, 0.f, 0.f};
    const bf16x8* wp = (const bf16x8*)Wsw1 + lane;
#pragma unroll
    for (int t = 0; t < 4; t++) {
        bf16x8 b = wp[(wid * 4 + t) * 64];
        acc[t] = __builtin_amdgcn_mfma_f32_16x16x32_bf16(a, b, acc[t], 0, 0, 0);
    }

    // ---- phase 4: C -> LDS (bf16, swizzled [16][512B]) ----
#pragma unroll
    for (int t = 0; t < 4; t++) {
        int col = (wid * 4 + t) * 16 + m;
#pragma unroll
        for (int r = 0; r < 4; r++) {
            int row = g * 4 + r;
            *(u16*)(ldsb + row * 512 + ((col * 2) ^ ((row & 7) << 4))) = f2b(acc[t][r]);
        }
    }
    __syncthreads();

    // ---- phase 5: epilogue relu + bias (nt store: don't pollute L3) ----
    {
        int row = threadIdx.x >> 4;
        int cb0 = (threadIdx.x & 15) * 16;
#pragma unroll
        for (int p = 0; p < 2; p++) {
            int cb = cb0 + p * 256;
            ushort8 c = *(const ushort8*)(ldsb + row * 512 + (cb ^ ((row & 7) << 4)));
            int gcol = cb >> 1;
            size_t gidx = (size_t)(row0 + row) * EMB + gcol;
            float4 bq0 = *(const float4*)&bias[gcol];
            float4 bq1 = *(const float4*)&bias[gcol + 4];
            float bb[8] = {bq0.x, bq0.y, bq0.z, bq0.w, bq1.x, bq1.y, bq1.z, bq1.w};
            ushort8 o;
#pragma unroll
            for (int j = 0; j < 8; j++)
                o[j] = f2b(fmaxf(b2f(c[j]) + bb[j], 0.f));
            nt_store16(&Hout[gidx], o);
        }
    }
}

// ---------------- fused GCN layer (2,3) ----------------
// Hout[r,:] = relu( (sum_{e: dst=r} Hin[src_e,:]) @ W.T + bias ) + Hin[r,:]
// Merged edge-stream gather; Hout via non-temporal stores (keep L3 for the gather set).
__global__ __launch_bounds__(256, 8) void fused_gcn(const u16* __restrict__ Hin,
                                                    const int* __restrict__ rowptr,
                                                    const int* __restrict__ csr,
                                                    const u16* __restrict__ Wsw,
                                                    const float* __restrict__ bias,
                                                    u16* __restrict__ Hout) {
    __shared__ __attribute__((aligned(16))) u16 lds[16][256];  // 8 KB
    const int wid = threadIdx.x >> 6;
    const int lane = threadIdx.x & 63;
    const int row0 = blockIdx.x * 16;
    char* ldsb = (char*)lds;
    const char* hbase = (const char*)Hin;
    const int laneByte = lane * 8;

    // ---- phase 1: merged-stream gather (all control in SGPRs) ----
    const int rbase = row0 + wid * 4;
    int s0 = RFL(rowptr[rbase + 0]);
    int t0 = RFL(rowptr[rbase + 1]);
    int t1 = RFL(rowptr[rbase + 2]);
    int t2 = RFL(rowptr[rbase + 3]);
    int t3 = RFL(rowptr[rbase + 4]);

    float4 ar0 = make_float4(0.f, 0.f, 0.f, 0.f);
    float4 ar1 = ar0, ar2 = ar0, ar3 = ar0;

    int idx[8];
#pragma unroll
    for (int d = 0; d < 8; d++) {
        int ce = s0 + d;
        if (ce > t3 - 1) ce = t3 - 1;
        if (ce < 0) ce = 0;
        idx[d] = RFL(csr[ce]);
    }
    int ee = s0;
    while (ee < t3) {
        uint2 v[8];
#pragma unroll
        for (int d = 0; d < 8; d++)
            v[d] = *(const uint2*)(hbase + (size_t)idx[d] * (EMB * 2) + laneByte);
        int eb = ee;
        ee += 8;
#pragma unroll
        for (int d = 0; d < 8; d++) {
            int ce = ee + d;
            if (ce > t3 - 1) ce = t3 - 1;
            if (ce < 0) ce = 0;
            idx[d] = RFL(csr[ce]);
        }
#pragma unroll
        for (int d = 0; d < 8; d++) {
            int ed = eb + d;
            if (ed < t3) {  // wave-uniform
                union { unsigned u; float f; } l0, h0, l1, h1;
                l0.u = v[d].x << 16; h0.u = v[d].x & 0xffff0000u;
                l1.u = v[d].y << 16; h1.u = v[d].y & 0xffff0000u;
                if (ed < t0)      { ar0.x += l0.f; ar0.y += h0.f; ar0.z += l1.f; ar0.w += h1.f; }
                else if (ed < t1) { ar1.x += l0.f; ar1.y += h0.f; ar1.z += l1.f; ar1.w += h1.f; }
                else if (ed < t2) { ar2.x += l0.f; ar2.y += h0.f; ar2.z += l1.f; ar2.w += h1.f; }
                else              { ar3.x += l0.f; ar3.y += h0.f; ar3.z += l1.f; ar3.w += h1.f; }
            }
        }
    }

    // write aggregated rows to LDS (bf16, swizzled)
    {
        float4 ars[4] = {ar0, ar1, ar2, ar3};
#pragma unroll
        for (int r = 0; r < 4; r++) {
            int li = wid * 4 + r;
            unsigned px = (unsigned)f2b(ars[r].x) | ((unsigned)f2b(ars[r].y) << 16);
            unsigned py = (unsigned)f2b(ars[r].z) | ((unsigned)f2b(ars[r].w) << 16);
            *(uint2*)(ldsb + li * 512 + (laneByte ^ ((li & 7) << 4))) = make_uint2(px, py);
        }
    }
    __syncthreads();

    // ---- phase 2: A fragments ----
    const int m = lane & 15;
    const int g = lane >> 4;
    bf16x8 a[8];
#pragma unroll
    for (int ks = 0; ks < 8; ks++) {
        int boff = (g * 16 + ks * 64) ^ ((m & 7) << 4);
        a[ks] = *(const bf16x8*)(ldsb + m * 512 + boff);
    }
    __syncthreads();

    // ---- phase 3: MFMA, wave owns col-tiles wid*4..wid*4+3 ----
    f32x4 acc2[4];
#pragma unroll
    for (int t = 0; t < 4; t++) acc2[t] = (f32x4){0.f, 0.f, 0.f, 0.f};
    const bf16x8* wp = (const bf16x8*)Wsw + lane;
#pragma unroll
    for (int t = 0; t < 4; t++) {
        int nt = wid * 4 + t;
        bf16x8 b[8];
#pragma unroll
        for (int ks = 0; ks < 8; ks++) b[ks] = wp[(nt * 8 + ks) * 64];
#pragma unroll
        for (int ks = 0; ks < 8; ks++)
            acc2[t] = __builtin_amdgcn_mfma_f32_16x16x32_bf16(a[ks], b[ks], acc2[t], 0, 0, 0);
    }

    // ---- phase 4: C -> LDS (bf16, swizzled) ----
#pragma unroll
    for (int t = 0; t < 4; t++) {
        int col = (wid * 4 + t) * 16 + m;
#pragma unroll
        for (int r = 0; r < 4; r++) {
            int row = g * 4 + r;
            *(u16*)(ldsb + row * 512 + ((col * 2) ^ ((row & 7) << 4))) = f2b(acc2[t][r]);
        }
    }
    __syncthreads();

    // ---- phase 5: epilogue relu + bias + residual (nt store for Hout) ----
    {
        int row = threadIdx.x >> 4;
        int cb0 = (threadIdx.x & 15) * 16;
#pragma unroll
        for (int p = 0; p < 2; p++) {
            int cb = cb0 + p * 256;
            ushort8 c = *(const ushort8*)(ldsb + row * 512 + (cb ^ ((row & 7) << 4)));
            int gcol = cb >> 1;
            size_t gidx = (size_t)(row0 + row) * EMB + gcol;
            ushort8 hres = *(const ushort8*)&Hin[gidx];
            float4 bq0 = *(const float4*)&bias[gcol];
            float4 bq1 = *(const float4*)&bias[gcol + 4];
            float bb[8] = {bq0.x, bq0.y, bq0.z, bq0.w, bq1.x, bq1.y, bq1.z, bq1.w};
            ushort8 o;
#pragma unroll
            for (int j = 0; j < 8; j++)
                o[j] = f2b(fmaxf(b2f(c[j]) + bb[j], 0.f) + b2f(hres[j]));
            nt_store16(&Hout[gidx], o);
        }
    }
}

// ---------------- pooling + head (fused) ----------------

__global__ void graph_bounds(const int* __restrict__ seg, int* __restrict__ gs, int n, int B) {
    int i = blockIdx.x * 256 + threadIdx.x;
    if (i >= n) return;
    int c = seg[i];
    int p = (i == 0) ? -1 : seg[i - 1];
    for (int b = p + 1; b <= c; b++) gs[b] = i;
    if (i == n - 1) {
        for (int b = c + 1; b <= B; b++) gs[b] = n;
    }
}

__global__ __launch_bounds__(256) void pool_head(const u16* __restrict__ h, const int* __restrict__ gs,
                                                 const float* __restrict__ Wp1, const float* __restrict__ Wp2,
                                                 const float* __restrict__ bp2, float* __restrict__ out) {
    __shared__ float gpq[4][EMB];
    __shared__ float gp[EMB];
    __shared__ float red[HID];
    int b = blockIdx.x, t = threadIdx.x;
    int s = gs[b], e = gs[b + 1];
    int q = t >> 6, ch4 = (t & 63) * 4;
    float a0 = 0.f, a1 = 0.f, a2 = 0.f, a3 = 0.f;
    int r = s + q;
    for (; r + 4 < e; r += 8) {
        ushort4 va = *(const ushort4*)&h[(size_t)r * EMB + ch4];
        ushort4 vb = *(const ushort4*)&h[(size_t)(r + 4) * EMB + ch4];
        a0 += b2f(va.x) + b2f(vb.x);
        a1 += b2f(va.y) + b2f(vb.y);
        a2 += b2f(va.z) + b2f(vb.z);
        a3 += b2f(va.w) + b2f(vb.w);
    }
    if (r < e) {
        ushort4 va = *(const ushort4*)&h[(size_t)r * EMB + ch4];
        a0 += b2f(va.x); a1 += b2f(va.y); a2 += b2f(va.z); a3 += b2f(va.w);
    }
    *(float4*)&gpq[q][ch4] = make_float4(a0, a1, a2, a3);
    __syncthreads();
    gp[t] = gpq[0][t] + gpq[1][t] + gpq[2][t] + gpq[3][t];
    __syncthreads();
    if (t < HID) {
        float acc = 0.f;
        const float4* wr = (const float4*)&Wp1[(size_t)t * EMB];
        const float4* gp4 = (const float4*)gp;
#pragma unroll 8
        for (int k = 0; k < EMB / 4; k++) {
            float4 w = wr[k], gg = gp4[k];
            acc += w.x * gg.x + w.y * gg.y + w.z * gg.z + w.w * gg.w;
        }
        red[t] = fmaxf(acc, 0.f) * Wp2[t];
    }
    __syncthreads();
    for (int off = 64; off > 0; off >>= 1) {
        if (t < off) red[t] += red[t + off];
        __syncthreads();
    }
    if (t == 0) out[b] = red[0] + bp2[0];
}

// ---------------- launch ----------------

extern "C" void kernel_launch(void* const* d_in, const int* in_sizes, int n_in,
                              void* d_out, int out_size, void* d_ws, size_t ws_size,
                              hipStream_t stream) {
    const float* x    = (const float*)d_in[0];
    const int*   src  = (const int*)d_in[1];
    const int*   dst  = (const int*)d_in[2];
    const int*   seg  = (const int*)d_in[3];
    const float* W_emb= (const float*)d_in[4];
    const float* W1   = (const float*)d_in[5];
    const float* b1   = (const float*)d_in[6];
    const float* W2   = (const float*)d_in[7];
    const float* b2   = (const float*)d_in[8];
    const float* W3   = (const float*)d_in[9];
    const float* b3   = (const float*)d_in[10];
    const float* Wp1  = (const float*)d_in[11];
    const float* Wp2  = (const float*)d_in[12];
    const float* bp2  = (const float*)d_in[13];
    float* out = (float*)d_out;

    char* ws = (char*)d_ws;
    size_t off = 0;
    auto alloc = [&](size_t bytes) -> void* {
        void* p = ws + off;
        off = (off + bytes + 255) & ~(size_t)255;
        return p;
    };
    const int N = N_NODES, E = N_EDGES, G = N_GRAPHS;
    u16* hA     = (u16*)alloc((size_t)N * EMB * 2);
    u16* hB     = (u16*)alloc((size_t)N * EMB * 2);
    u16* h0     = (u16*)alloc((size_t)N * IN_CH * 2);
    u16* Wsw1   = (u16*)alloc(16 * 64 * 8 * 2);
    u16* Wsw2   = (u16*)alloc(256 * 256 * 2);
    u16* Wsw3   = (u16*)alloc(256 * 256 * 2);
    int* rowptr = (int*)alloc((size_t)(N + 1) * 4);
    int* deg    = (int*)alloc((size_t)N * 4);
    int* csr    = (int*)alloc((size_t)E * 4);
    int* partials = (int*)alloc(1024 * 4);
    int* gs     = (int*)alloc((size_t)(G + 1) * 4);

    if (off > ws_size) return;  // clean failure instead of OOB crash

    // CSR build (by dst); fill_csr consumes deg counts via atomicSub
    hipMemsetAsync(deg, 0, (size_t)N * 4, stream);
    count_deg<<<E / 256, 256, 0, stream>>>(dst, deg, E);
    scan_a<<<196, 256, 0, stream>>>(deg, rowptr + 1, partials, N);
    scan_b<<<1, 256, 0, stream>>>(partials, 196);
    scan_c<<<782, 256, 0, stream>>>(rowptr, partials, N);
    fill_csr<<<E / 256, 256, 0, stream>>>(src, dst, rowptr, deg, csr, E);

    // weight packing
    swizzle_w1<<<4, 256, 0, stream>>>(W1, Wsw1);
    swizzle_w23<<<64, 256, 0, stream>>>(W2, W3, Wsw2, Wsw3);

    // layer 1: h0 = bf16(x @ We.T); hA = relu(agg(h0) @ W1.T + b1)
    emb8<<<782, 256, 0, stream>>>(x, W_emb, h0, N);
    fused_l1<<<N / 16, 256, 0, stream>>>(h0, rowptr, csr, Wsw1, b1, hA);

    // layer 2: hB = relu(agg(hA) @ W2.T + b2) + hA
    fused_gcn<<<N / 16, 256, 0, stream>>>(hA, rowptr, csr, Wsw2, b2, hB);
    // layer 3: hA = relu(agg(hB) @ W3.T + b3) + hB
    fused_gcn<<<N / 16, 256, 0, stream>>>(hB, rowptr, csr, Wsw3, b3, hA);

    // pooling + head
    graph_bounds<<<782, 256, 0, stream>>>(seg, gs, N, G);
    pool_head<<<G, 256, 0, stream>>>(hA, gs, Wp1, Wp2, bp2, out);
}

// Round 11
// 433.052 us; speedup vs baseline: 1.0750x; 1.0750x over previous
//
#include <hip/hip_runtime.h>
#include <hip/hip_bf16.h>

#define N_NODES 200000
#define N_EDGES 800000
#define N_GRAPHS 4000
#define D_N 35
#define IN_CH 8
#define EMB 256
#define HID 128

typedef unsigned short u16;
typedef __attribute__((ext_vector_type(8))) short bf16x8;
typedef __attribute__((ext_vector_type(8))) unsigned short ushort8;
typedef __attribute__((ext_vector_type(4))) float f32x4;
typedef __attribute__((ext_vector_type(2))) float f32x2;

__device__ __forceinline__ float b2f(u16 u) {
    union { float f; unsigned v; } x; x.v = ((unsigned)u) << 16; return x.f;
}
__device__ __forceinline__ u16 f2b(float f) {
    union { float f; unsigned v; } x; x.f = f;
    unsigned r = x.v + 0x7fff + ((x.v >> 16) & 1);  // round-nearest-even
    return (u16)(r >> 16);
}
// unpack u32 (2 bf16) -> f32x2 {lo, hi}
__device__ __forceinline__ f32x2 unpk(unsigned u) {
    union { unsigned v[2]; f32x2 f; } r;
    r.v[0] = u << 16; r.v[1] = u & 0xffff0000u;
    return r.f;
}
#define RFL(v) __builtin_amdgcn_readfirstlane(v)

// ---------------- CSR build ----------------

__global__ void count_deg(const int* __restrict__ dst, int* __restrict__ deg, int n) {
    int e = blockIdx.x * 256 + threadIdx.x;
    if (e < n) atomicAdd(&deg[dst[e]], 1);
}

__global__ __launch_bounds__(256) void scan_a(const int* __restrict__ deg, int* __restrict__ incl1,
                                              int* __restrict__ partials, int n) {
    __shared__ int s[256];
    int tid = threadIdx.x;
    int base = blockIdx.x * 1024;
    int v[4]; int sum = 0;
#pragma unroll
    for (int j = 0; j < 4; j++) {
        int idx = base + tid * 4 + j;
        v[j] = (idx < n) ? deg[idx] : 0;
        sum += v[j];
    }
    s[tid] = sum; __syncthreads();
    for (int off = 1; off < 256; off <<= 1) {
        int t = (tid >= off) ? s[tid - off] : 0;
        __syncthreads();
        s[tid] += t;
        __syncthreads();
    }
    int run = s[tid] - sum;
#pragma unroll
    for (int j = 0; j < 4; j++) {
        int idx = base + tid * 4 + j;
        run += v[j];
        if (idx < n) incl1[idx] = run;
    }
    if (tid == 255) partials[blockIdx.x] = s[255];
}

__global__ __launch_bounds__(256) void scan_b(int* __restrict__ partials, int np) {
    __shared__ int s[256];
    int tid = threadIdx.x;
    int v = (tid < np) ? partials[tid] : 0;
    s[tid] = v; __syncthreads();
    for (int off = 1; off < 256; off <<= 1) {
        int t = (tid >= off) ? s[tid - off] : 0;
        __syncthreads();
        s[tid] += t;
        __syncthreads();
    }
    if (tid < np) partials[tid] = s[tid] - v;
}

__global__ void scan_c(int* __restrict__ rowptr, const int* __restrict__ partials, int n) {
    int i = blockIdx.x * 256 + threadIdx.x;
    if (i < n) rowptr[1 + i] += partials[i >> 10];
    if (i == 0) rowptr[0] = 0;
}

// slot-allocate by atomicSub on counts (cnt ends at 0; intra-row order nondeterministic, sum unchanged)
__global__ void fill_csr(const int* __restrict__ src, const int* __restrict__ dst,
                         const int* __restrict__ rowptr, int* __restrict__ cnt,
                         int* __restrict__ csr, int n) {
    int e = blockIdx.x * 256 + threadIdx.x;
    if (e >= n) return;
    int d = dst[e];
    int p = atomicSub(&cnt[d], 1) - 1;
    csr[rowptr[d] + p] = src[e];
}

// ---------------- weight packing ----------------

__global__ __launch_bounds__(256) void swizzle_w23(const float* __restrict__ W2, const float* __restrict__ W3,
                                                   u16* __restrict__ Wsw2, u16* __restrict__ Wsw3) {
    int t = blockIdx.x * 256 + threadIdx.x;  // 16384 threads
    const float* W = (t < 8192) ? W2 : W3;
    u16* Wsw = (t < 8192) ? Wsw2 : Wsw3;
    int tl = t & 8191;
    int lane = tl & 63;
    int n = ((tl >> 9) << 4) + (lane & 15);
    int k0 = (((tl >> 6) & 7) << 5) + ((lane >> 4) << 3);
    u16 v[8];
#pragma unroll
    for (int j = 0; j < 8; j++) v[j] = f2b(W[(size_t)n * 256 + k0 + j]);
    ushort4* o = (ushort4*)&Wsw[(size_t)tl * 8];
    o[0] = make_ushort4(v[0], v[1], v[2], v[3]);
    o[1] = make_ushort4(v[4], v[5], v[6], v[7]);
}

__global__ __launch_bounds__(256) void swizzle_w1(const float* __restrict__ W1, u16* __restrict__ Wsw) {
    int t = blockIdx.x * 256 + threadIdx.x;  // 1024 threads
    int lane = t & 63;
    int nt = t >> 6;
    int n = nt * 16 + (lane & 15);
    int g = lane >> 4;
    u16 v[8];
#pragma unroll
    for (int j = 0; j < 8; j++) v[j] = (g == 0) ? f2b(W1[n * 8 + j]) : (u16)0;
    ushort4* o = (ushort4*)&Wsw[(size_t)t * 8];
    o[0] = make_ushort4(v[0], v[1], v[2], v[3]);
    o[1] = make_ushort4(v[4], v[5], v[6], v[7]);
}

// ---------------- emb: h0 = bf16(x @ We.T)  [N,8] ----------------
__global__ __launch_bounds__(256) void emb8(const float* __restrict__ x, const float* __restrict__ We,
                                            u16* __restrict__ h0, int n) {
    __shared__ float ws[IN_CH * D_N];
    int tid = threadIdx.x;
    for (int i = tid; i < IN_CH * D_N; i += 256) ws[i] = We[i];
    __syncthreads();
    int node = blockIdx.x * 256 + tid;
    if (node >= n) return;
    float xr[D_N];
    const float* xp = &x[(size_t)node * D_N];
#pragma unroll
    for (int k = 0; k < D_N; k++) xr[k] = xp[k];
    ushort8 o;
#pragma unroll
    for (int j = 0; j < IN_CH; j++) {
        float acc = 0.f;
#pragma unroll
        for (int k = 0; k < D_N; k++) acc += xr[k] * ws[j * D_N + k];
        o[j] = f2b(acc);
    }
    *(ushort8*)&h0[(size_t)node * IN_CH] = o;
}

// ---------------- fused layer 1: agg8 + MFMA GEMM (8->256) ----------------
__global__ __launch_bounds__(256) void fused_l1(const u16* __restrict__ h0,
                                                const int* __restrict__ rowptr,
                                                const int* __restrict__ csr,
                                                const u16* __restrict__ Wsw1,
                                                const float* __restrict__ bias,
                                                u16* __restrict__ Hout) {
    __shared__ __attribute__((aligned(16))) u16 lds[16][256];  // 8 KB
    const int wid = threadIdx.x >> 6;
    const int lane = threadIdx.x & 63;
    const int row0 = blockIdx.x * 16;
    char* ldsb = (char*)lds;
    const char* h0c = (const char*)h0;

    // ---- phase 1: lane halves own 2 rows concurrently (8 slots x 4 ch-lanes) ----
    const int halfsel = lane >> 5;
    const int slot = (lane & 31) >> 2;
    const int cid2 = (lane & 3) * 4;
    const int rbase = row0 + wid * 4;
#pragma unroll
    for (int rp = 0; rp < 2; rp++) {
        int r = rp * 2 + halfsel;
        int er = rowptr[rbase + r];
        int tr = rowptr[rbase + r + 1];
        float2 acc = make_float2(0.f, 0.f);
        for (int eb = er; __any(eb < tr); eb += 8) {
            int e = eb + slot;
            int ce = e < tr ? e : tr - 1;
            if (ce < 0) ce = 0;
            int sidx = csr[ce];
            unsigned v = *(const unsigned*)(h0c + (size_t)sidx * 16 + cid2);
            if (e < tr) {
                union { unsigned u; float f; } lo, hi;
                lo.u = v << 16; hi.u = v & 0xffff0000u;
                acc.x += lo.f; acc.y += hi.f;
            }
        }
        acc.x += __shfl_xor(acc.x, 4, 64);  acc.y += __shfl_xor(acc.y, 4, 64);
        acc.x += __shfl_xor(acc.x, 8, 64);  acc.y += __shfl_xor(acc.y, 8, 64);
        acc.x += __shfl_xor(acc.x, 16, 64); acc.y += __shfl_xor(acc.y, 16, 64);
        if ((lane & 31) < 4) {
            unsigned pk = (unsigned)f2b(acc.x) | ((unsigned)f2b(acc.y) << 16);
            *(unsigned*)(ldsb + (wid * 4 + r) * 16 + cid2) = pk;
        }
    }
    __syncthreads();

    // ---- phase 2: A fragment (K=32: k<8 real, rest zero) ----
    const int m = lane & 15;
    const int g = lane >> 4;
    bf16x8 a = {};
    if (g == 0) a = *(const bf16x8*)(ldsb + m * 16);
    __syncthreads();

    // ---- phase 3: 1 MFMA per col-tile ----
    f32x4 acc[4];
#pragma unroll
    for (int t = 0; t < 4; t++) acc[t] = (f32x4){0.f, 0.f, 0.f, 0.f};
    const bf16x8* wp = (const bf16x8*)Wsw1 + lane;
#pragma unroll
    for (int t = 0; t < 4; t++) {
        bf16x8 b = wp[(wid * 4 + t) * 64];
        acc[t] = __builtin_amdgcn_mfma_f32_16x16x32_bf16(a, b, acc[t], 0, 0, 0);
    }

    // ---- phase 4: C -> LDS (bf16, swizzled [16][512B]) ----
#pragma unroll
    for (int t = 0; t < 4; t++) {
        int col = (wid * 4 + t) * 16 + m;
#pragma unroll
        for (int r = 0; r < 4; r++) {
            int row = g * 4 + r;
            *(u16*)(ldsb + row * 512 + ((col * 2) ^ ((row & 7) << 4))) = f2b(acc[t][r]);
        }
    }
    __syncthreads();

    // ---- phase 5: epilogue relu + bias ----
    {
        int row = threadIdx.x >> 4;
        int cb0 = (threadIdx.x & 15) * 16;
#pragma unroll
        for (int p = 0; p < 2; p++) {
            int cb = cb0 + p * 256;
            ushort8 c = *(const ushort8*)(ldsb + row * 512 + (cb ^ ((row & 7) << 4)));
            int gcol = cb >> 1;
            size_t gidx = (size_t)(row0 + row) * EMB + gcol;
            float4 bq0 = *(const float4*)&bias[gcol];
            float4 bq1 = *(const float4*)&bias[gcol + 4];
            float bb[8] = {bq0.x, bq0.y, bq0.z, bq0.w, bq1.x, bq1.y, bq1.z, bq1.w};
            ushort8 o;
#pragma unroll
            for (int j = 0; j < 8; j++)
                o[j] = f2b(fmaxf(b2f(c[j]) + bb[j], 0.f));
            *(ushort8*)&Hout[gidx] = o;
        }
    }
}

// ---------------- fused GCN layer 2 ----------------
__global__ __launch_bounds__(256, 8) void fused_gcn(const u16* __restrict__ Hin,
                                                    const int* __restrict__ rowptr,
                                                    const int* __restrict__ csr,
                                                    const u16* __restrict__ Wsw,
                                                    const float* __restrict__ bias,
                                                    u16* __restrict__ Hout) {
    __shared__ __attribute__((aligned(16))) u16 lds[16][256];  // 8 KB
    const int wid = threadIdx.x >> 6;
    const int lane = threadIdx.x & 63;
    const int row0 = blockIdx.x * 16;
    char* ldsb = (char*)lds;
    const char* hbase = (const char*)Hin;
    const int laneByte = lane * 8;

    // ---- phase 1: merged-stream gather (control in SGPRs) ----
    const int rbase = row0 + wid * 4;
    int s0 = RFL(rowptr[rbase + 0]);
    int t0 = RFL(rowptr[rbase + 1]);
    int t1 = RFL(rowptr[rbase + 2]);
    int t2 = RFL(rowptr[rbase + 3]);
    int t3 = RFL(rowptr[rbase + 4]);

    f32x2 r0a = {0.f, 0.f}, r0b = {0.f, 0.f};
    f32x2 r1a = {0.f, 0.f}, r1b = {0.f, 0.f};
    f32x2 r2a = {0.f, 0.f}, r2b = {0.f, 0.f};
    f32x2 r3a = {0.f, 0.f}, r3b = {0.f, 0.f};

    int idx[8];
#pragma unroll
    for (int d = 0; d < 8; d++) {
        int ce = s0 + d;
        if (ce > t3 - 1) ce = t3 - 1;
        if (ce < 0) ce = 0;
        idx[d] = RFL(csr[ce]);
    }
    int ee = s0;
    while (ee < t3) {
        uint2 v[8];
#pragma unroll
        for (int d = 0; d < 8; d++)
            v[d] = *(const uint2*)(hbase + (size_t)idx[d] * (EMB * 2) + laneByte);
        int eb = ee;
        ee += 8;
#pragma unroll
        for (int d = 0; d < 8; d++) {
            int ce = ee + d;
            if (ce > t3 - 1) ce = t3 - 1;
            if (ce < 0) ce = 0;
            idx[d] = RFL(csr[ce]);
        }
#pragma unroll
        for (int d = 0; d < 8; d++) {
            int ed = eb + d;
            if (ed < t3) {  // wave-uniform
                f32x2 ux = unpk(v[d].x), uy = unpk(v[d].y);
                if (ed < t0)      { r0a += ux; r0b += uy; }
                else if (ed < t1) { r1a += ux; r1b += uy; }
                else if (ed < t2) { r2a += ux; r2b += uy; }
                else              { r3a += ux; r3b += uy; }
            }
        }
    }

    // write aggregated rows to LDS (bf16, swizzled)
    {
        f32x2 lo[4] = {r0a, r1a, r2a, r3a};
        f32x2 hi[4] = {r0b, r1b, r2b, r3b};
#pragma unroll
        for (int r = 0; r < 4; r++) {
            int li = wid * 4 + r;
            unsigned px = (unsigned)f2b(lo[r][0]) | ((unsigned)f2b(lo[r][1]) << 16);
            unsigned py = (unsigned)f2b(hi[r][0]) | ((unsigned)f2b(hi[r][1]) << 16);
            *(uint2*)(ldsb + li * 512 + (laneByte ^ ((li & 7) << 4))) = make_uint2(px, py);
        }
    }
    __syncthreads();

    // ---- phase 2: A fragments ----
    const int m = lane & 15;
    const int g = lane >> 4;
    bf16x8 a[8];
#pragma unroll
    for (int ks = 0; ks < 8; ks++) {
        int boff = (g * 16 + ks * 64) ^ ((m & 7) << 4);
        a[ks] = *(const bf16x8*)(ldsb + m * 512 + boff);
    }
    __syncthreads();

    // ---- phase 3: MFMA ----
    f32x4 acc2[4];
#pragma unroll
    for (int t = 0; t < 4; t++) acc2[t] = (f32x4){0.f, 0.f, 0.f, 0.f};
    const bf16x8* wp = (const bf16x8*)Wsw + lane;
#pragma unroll
    for (int t = 0; t < 4; t++) {
        int nt = wid * 4 + t;
        bf16x8 b[8];
#pragma unroll
        for (int ks = 0; ks < 8; ks++) b[ks] = wp[(nt * 8 + ks) * 64];
#pragma unroll
        for (int ks = 0; ks < 8; ks++)
            acc2[t] = __builtin_amdgcn_mfma_f32_16x16x32_bf16(a[ks], b[ks], acc2[t], 0, 0, 0);
    }

    // ---- phase 4: C -> LDS (bf16, swizzled) ----
#pragma unroll
    for (int t = 0; t < 4; t++) {
        int col = (wid * 4 + t) * 16 + m;
#pragma unroll
        for (int r = 0; r < 4; r++) {
            int row = g * 4 + r;
            *(u16*)(ldsb + row * 512 + ((col * 2) ^ ((row & 7) << 4))) = f2b(acc2[t][r]);
        }
    }
    __syncthreads();

    // ---- phase 5: epilogue relu + bias + residual ----
    {
        int row = threadIdx.x >> 4;
        int cb0 = (threadIdx.x & 15) * 16;
#pragma unroll
        for (int p = 0; p < 2; p++) {
            int cb = cb0 + p * 256;
            ushort8 c = *(const ushort8*)(ldsb + row * 512 + (cb ^ ((row & 7) << 4)));
            int gcol = cb >> 1;
            size_t gidx = (size_t)(row0 + row) * EMB + gcol;
            ushort8 hres = *(const ushort8*)&Hin[gidx];
            float4 bq0 = *(const float4*)&bias[gcol];
            float4 bq1 = *(const float4*)&bias[gcol + 4];
            float bb[8] = {bq0.x, bq0.y, bq0.z, bq0.w, bq1.x, bq1.y, bq1.z, bq1.w};
            ushort8 o;
#pragma unroll
            for (int j = 0; j < 8; j++)
                o[j] = f2b(fmaxf(b2f(c[j]) + bb[j], 0.f) + b2f(hres[j]));
            *(ushort8*)&Hout[gidx] = o;
        }
    }
}

// ---------------- fused GCN layer 3 + pooling ----------------
// Computes final h rows in LDS, then segment-sums into g via per-group atomics.
// No Hout store at all (h after layer 3 is only consumed by pooling).
__global__ __launch_bounds__(256, 8) void fused_gcn_pool(const u16* __restrict__ Hin,
                                                         const int* __restrict__ rowptr,
                                                         const int* __restrict__ csr,
                                                         const u16* __restrict__ Wsw,
                                                         const float* __restrict__ bias,
                                                         const int* __restrict__ seg,
                                                         float* __restrict__ g) {
    __shared__ __attribute__((aligned(16))) u16 lds[16][256];  // 8 KB
    __shared__ int segs[16];
    const int wid = threadIdx.x >> 6;
    const int lane = threadIdx.x & 63;
    const int row0 = blockIdx.x * 16;
    char* ldsb = (char*)lds;
    const char* hbase = (const char*)Hin;
    const int laneByte = lane * 8;

    // ---- phase 1: merged-stream gather ----
    const int rbase = row0 + wid * 4;
    int s0 = RFL(rowptr[rbase + 0]);
    int t0 = RFL(rowptr[rbase + 1]);
    int t1 = RFL(rowptr[rbase + 2]);
    int t2 = RFL(rowptr[rbase + 3]);
    int t3 = RFL(rowptr[rbase + 4]);

    f32x2 r0a = {0.f, 0.f}, r0b = {0.f, 0.f};
    f32x2 r1a = {0.f, 0.f}, r1b = {0.f, 0.f};
    f32x2 r2a = {0.f, 0.f}, r2b = {0.f, 0.f};
    f32x2 r3a = {0.f, 0.f}, r3b = {0.f, 0.f};

    int idx[8];
#pragma unroll
    for (int d = 0; d < 8; d++) {
        int ce = s0 + d;
        if (ce > t3 - 1) ce = t3 - 1;
        if (ce < 0) ce = 0;
        idx[d] = RFL(csr[ce]);
    }
    int ee = s0;
    while (ee < t3) {
        uint2 v[8];
#pragma unroll
        for (int d = 0; d < 8; d++)
            v[d] = *(const uint2*)(hbase + (size_t)idx[d] * (EMB * 2) + laneByte);
        int eb = ee;
        ee += 8;
#pragma unroll
        for (int d = 0; d < 8; d++) {
            int ce = ee + d;
            if (ce > t3 - 1) ce = t3 - 1;
            if (ce < 0) ce = 0;
            idx[d] = RFL(csr[ce]);
        }
#pragma unroll
        for (int d = 0; d < 8; d++) {
            int ed = eb + d;
            if (ed < t3) {
                f32x2 ux = unpk(v[d].x), uy = unpk(v[d].y);
                if (ed < t0)      { r0a += ux; r0b += uy; }
                else if (ed < t1) { r1a += ux; r1b += uy; }
                else if (ed < t2) { r2a += ux; r2b += uy; }
                else              { r3a += ux; r3b += uy; }
            }
        }
    }

    {
        f32x2 lo[4] = {r0a, r1a, r2a, r3a};
        f32x2 hi[4] = {r0b, r1b, r2b, r3b};
#pragma unroll
        for (int r = 0; r < 4; r++) {
            int li = wid * 4 + r;
            unsigned px = (unsigned)f2b(lo[r][0]) | ((unsigned)f2b(lo[r][1]) << 16);
            unsigned py = (unsigned)f2b(hi[r][0]) | ((unsigned)f2b(hi[r][1]) << 16);
            *(uint2*)(ldsb + li * 512 + (laneByte ^ ((li & 7) << 4))) = make_uint2(px, py);
        }
    }
    if (threadIdx.x < 16) segs[threadIdx.x] = seg[row0 + threadIdx.x];
    __syncthreads();

    // ---- phase 2: A fragments ----
    const int m = lane & 15;
    const int g_ = lane >> 4;
    bf16x8 a[8];
#pragma unroll
    for (int ks = 0; ks < 8; ks++) {
        int boff = (g_ * 16 + ks * 64) ^ ((m & 7) << 4);
        a[ks] = *(const bf16x8*)(ldsb + m * 512 + boff);
    }
    __syncthreads();

    // ---- phase 3: MFMA ----
    f32x4 acc2[4];
#pragma unroll
    for (int t = 0; t < 4; t++) acc2[t] = (f32x4){0.f, 0.f, 0.f, 0.f};
    const bf16x8* wp = (const bf16x8*)Wsw + lane;
#pragma unroll
    for (int t = 0; t < 4; t++) {
        int nt = wid * 4 + t;
        bf16x8 b[8];
#pragma unroll
        for (int ks = 0; ks < 8; ks++) b[ks] = wp[(nt * 8 + ks) * 64];
#pragma unroll
        for (int ks = 0; ks < 8; ks++)
            acc2[t] = __builtin_amdgcn_mfma_f32_16x16x32_bf16(a[ks], b[ks], acc2[t], 0, 0, 0);
    }

    // ---- phase 4: C -> LDS (bf16, swizzled) ----
#pragma unroll
    for (int t = 0; t < 4; t++) {
        int col = (wid * 4 + t) * 16 + m;
#pragma unroll
        for (int r = 0; r < 4; r++) {
            int row = g_ * 4 + r;
            *(u16*)(ldsb + row * 512 + ((col * 2) ^ ((row & 7) << 4))) = f2b(acc2[t][r]);
        }
    }
    __syncthreads();

    // ---- phase 5: final values (relu+bias+residual) back into LDS as bf16 ----
    {
        int row = threadIdx.x >> 4;
        int cb0 = (threadIdx.x & 15) * 16;
#pragma unroll
        for (int p = 0; p < 2; p++) {
            int cb = cb0 + p * 256;
            char* lp = ldsb + row * 512 + (cb ^ ((row & 7) << 4));
            ushort8 c = *(const ushort8*)lp;
            int gcol = cb >> 1;
            size_t gidx = (size_t)(row0 + row) * EMB + gcol;
            ushort8 hres = *(const ushort8*)&Hin[gidx];
            float4 bq0 = *(const float4*)&bias[gcol];
            float4 bq1 = *(const float4*)&bias[gcol + 4];
            float bb[8] = {bq0.x, bq0.y, bq0.z, bq0.w, bq1.x, bq1.y, bq1.z, bq1.w};
            ushort8 o;
#pragma unroll
            for (int j = 0; j < 8; j++)
                o[j] = f2b(fmaxf(b2f(c[j]) + bb[j], 0.f) + b2f(hres[j]));
            *(ushort8*)lp = o;
        }
    }
    __syncthreads();

    // ---- phase 6: segment-sum the 16 rows into g (thread = channel) ----
    {
        int ch = threadIdx.x;  // 0..255
        float acc = 0.f;
        int gprev = segs[0];
#pragma unroll
        for (int r = 0; r < 16; r++) {
            int gr = segs[r];  // block-uniform
            float v = b2f(*(const u16*)(ldsb + r * 512 + ((ch * 2) ^ ((r & 7) << 4))));
            if (gr != gprev) {
                atomicAdd(&g[(size_t)gprev * EMB + ch], acc);
                acc = 0.f;
                gprev = gr;
            }
            acc += v;
        }
        atomicAdd(&g[(size_t)gprev * EMB + ch], acc);
    }
}

// ---------------- head ----------------

__global__ __launch_bounds__(128) void head_only(const float* __restrict__ g, const float* __restrict__ Wp1,
                                                 const float* __restrict__ Wp2, const float* __restrict__ bp2,
                                                 float* __restrict__ out) {
    __shared__ float gsm[EMB];
    __shared__ float red[HID];
    int b = blockIdx.x, t = threadIdx.x;
    gsm[t] = g[(size_t)b * EMB + t];
    gsm[t + 128] = g[(size_t)b * EMB + t + 128];
    __syncthreads();
    float acc = 0.f;
    const float4* wr = (const float4*)&Wp1[(size_t)t * EMB];
    const float4* gp4 = (const float4*)gsm;
#pragma unroll 8
    for (int k = 0; k < EMB / 4; k++) {
        float4 w = wr[k], gg = gp4[k];
        acc += w.x * gg.x + w.y * gg.y + w.z * gg.z + w.w * gg.w;
    }
    red[t] = fmaxf(acc, 0.f) * Wp2[t];
    __syncthreads();
    for (int off = 64; off > 0; off >>= 1) {
        if (t < off) red[t] += red[t + off];
        __syncthreads();
    }
    if (t == 0) out[b] = red[0] + bp2[0];
}

// ---------------- launch ----------------

extern "C" void kernel_launch(void* const* d_in, const int* in_sizes, int n_in,
                              void* d_out, int out_size, void* d_ws, size_t ws_size,
                              hipStream_t stream) {
    const float* x    = (const float*)d_in[0];
    const int*   src  = (const int*)d_in[1];
    const int*   dst  = (const int*)d_in[2];
    const int*   seg  = (const int*)d_in[3];
    const float* W_emb= (const float*)d_in[4];
    const float* W1   = (const float*)d_in[5];
    const float* b1   = (const float*)d_in[6];
    const float* W2   = (const float*)d_in[7];
    const float* b2   = (const float*)d_in[8];
    const float* W3   = (const float*)d_in[9];
    const float* b3   = (const float*)d_in[10];
    const float* Wp1  = (const float*)d_in[11];
    const float* Wp2  = (const float*)d_in[12];
    const float* bp2  = (const float*)d_in[13];
    float* out = (float*)d_out;

    char* ws = (char*)d_ws;
    size_t off = 0;
    auto alloc = [&](size_t bytes) -> void* {
        void* p = ws + off;
        off = (off + bytes + 255) & ~(size_t)255;
        return p;
    };
    const int N = N_NODES, E = N_EDGES, G = N_GRAPHS;
    u16* hA     = (u16*)alloc((size_t)N * EMB * 2);
    u16* hB     = (u16*)alloc((size_t)N * EMB * 2);
    u16* h0     = (u16*)alloc((size_t)N * IN_CH * 2);
    u16* Wsw1   = (u16*)alloc(16 * 64 * 8 * 2);
    u16* Wsw2   = (u16*)alloc(256 * 256 * 2);
    u16* Wsw3   = (u16*)alloc(256 * 256 * 2);
    int* rowptr = (int*)alloc((size_t)(N + 1) * 4);
    int* deg    = (int*)alloc((size_t)N * 4);
    int* csr    = (int*)alloc((size_t)E * 4);
    int* partials = (int*)alloc(1024 * 4);
    float* gbuf = (float*)alloc((size_t)G * EMB * 4);

    if (off > ws_size) return;  // clean failure instead of OOB crash

    // CSR build (by dst)
    hipMemsetAsync(deg, 0, (size_t)N * 4, stream);
    count_deg<<<E / 256, 256, 0, stream>>>(dst, deg, E);
    scan_a<<<196, 256, 0, stream>>>(deg, rowptr + 1, partials, N);
    scan_b<<<1, 256, 0, stream>>>(partials, 196);
    scan_c<<<782, 256, 0, stream>>>(rowptr, partials, N);
    fill_csr<<<E / 256, 256, 0, stream>>>(src, dst, rowptr, deg, csr, E);

    // weight packing + g zero
    swizzle_w1<<<4, 256, 0, stream>>>(W1, Wsw1);
    swizzle_w23<<<64, 256, 0, stream>>>(W2, W3, Wsw2, Wsw3);
    hipMemsetAsync(gbuf, 0, (size_t)G * EMB * 4, stream);

    // layer 1: h0 = bf16(x @ We.T); hA = relu(agg(h0) @ W1.T + b1)
    emb8<<<782, 256, 0, stream>>>(x, W_emb, h0, N);
    fused_l1<<<N / 16, 256, 0, stream>>>(h0, rowptr, csr, Wsw1, b1, hA);

    // layer 2: hB = relu(agg(hA) @ W2.T + b2) + hA
    fused_gcn<<<N / 16, 256, 0, stream>>>(hA, rowptr, csr, Wsw2, b2, hB);
    // layer 3 + pooling: g += segsum( relu(agg(hB) @ W3.T + b3) + hB )
    fused_gcn_pool<<<N / 16, 256, 0, stream>>>(hB, rowptr, csr, Wsw3, b3, seg, gbuf);

    // head
    head_only<<<G, 128, 0, stream>>>(gbuf, Wp1, Wp2, bp2, out);
}

// Round 12
// 396.271 us; speedup vs baseline: 1.1747x; 1.0928x over previous
//
#include <hip/hip_runtime.h>
#include <hip/hip_bf16.h>

#define N_NODES 200000
#define N_EDGES 800000
#define N_GRAPHS 4000
#define D_N 35
#define IN_CH 8
#define EMB 256
#define HID 128

typedef unsigned short u16;
typedef __attribute__((ext_vector_type(8))) short bf16x8;
typedef __attribute__((ext_vector_type(8))) unsigned short ushort8;
typedef __attribute__((ext_vector_type(4))) float f32x4;
typedef __attribute__((ext_vector_type(2))) float f32x2;

__device__ __forceinline__ float b2f(u16 u) {
    union { float f; unsigned v; } x; x.v = ((unsigned)u) << 16; return x.f;
}
__device__ __forceinline__ u16 f2b(float f) {
    union { float f; unsigned v; } x; x.f = f;
    unsigned r = x.v + 0x7fff + ((x.v >> 16) & 1);  // round-nearest-even
    return (u16)(r >> 16);
}
// unpack u32 (2 bf16) -> f32x2 {lo, hi}
__device__ __forceinline__ f32x2 unpk(unsigned u) {
    union { unsigned v[2]; f32x2 f; } r;
    r.v[0] = u << 16; r.v[1] = u & 0xffff0000u;
    return r.f;
}
__device__ __forceinline__ unsigned pk2(f32x2 a) {
    return (unsigned)f2b(a[0]) | ((unsigned)f2b(a[1]) << 16);
}
#define RFL(v) __builtin_amdgcn_readfirstlane(v)

// ---------------- CSR build ----------------

__global__ void count_deg(const int* __restrict__ dst, int* __restrict__ deg, int n) {
    int e = blockIdx.x * 256 + threadIdx.x;
    if (e < n) atomicAdd(&deg[dst[e]], 1);
}

__global__ __launch_bounds__(256) void scan_a(const int* __restrict__ deg, int* __restrict__ incl1,
                                              int* __restrict__ partials, int n) {
    __shared__ int s[256];
    int tid = threadIdx.x;
    int base = blockIdx.x * 1024;
    int v[4]; int sum = 0;
#pragma unroll
    for (int j = 0; j < 4; j++) {
        int idx = base + tid * 4 + j;
        v[j] = (idx < n) ? deg[idx] : 0;
        sum += v[j];
    }
    s[tid] = sum; __syncthreads();
    for (int off = 1; off < 256; off <<= 1) {
        int t = (tid >= off) ? s[tid - off] : 0;
        __syncthreads();
        s[tid] += t;
        __syncthreads();
    }
    int run = s[tid] - sum;
#pragma unroll
    for (int j = 0; j < 4; j++) {
        int idx = base + tid * 4 + j;
        run += v[j];
        if (idx < n) incl1[idx] = run;
    }
    if (tid == 255) partials[blockIdx.x] = s[255];
}

__global__ __launch_bounds__(256) void scan_b(int* __restrict__ partials, int np) {
    __shared__ int s[256];
    int tid = threadIdx.x;
    int v = (tid < np) ? partials[tid] : 0;
    s[tid] = v; __syncthreads();
    for (int off = 1; off < 256; off <<= 1) {
        int t = (tid >= off) ? s[tid - off] : 0;
        __syncthreads();
        s[tid] += t;
        __syncthreads();
    }
    if (tid < np) partials[tid] = s[tid] - v;
}

__global__ void scan_c(int* __restrict__ rowptr, const int* __restrict__ partials, int n) {
    int i = blockIdx.x * 256 + threadIdx.x;
    if (i < n) rowptr[1 + i] += partials[i >> 10];
    if (i == 0) rowptr[0] = 0;
}

// slot-allocate by atomicSub on counts (intra-row order nondeterministic, sum unchanged)
__global__ void fill_csr(const int* __restrict__ src, const int* __restrict__ dst,
                         const int* __restrict__ rowptr, int* __restrict__ cnt,
                         int* __restrict__ csr, int n) {
    int e = blockIdx.x * 256 + threadIdx.x;
    if (e >= n) return;
    int d = dst[e];
    int p = atomicSub(&cnt[d], 1) - 1;
    csr[rowptr[d] + p] = src[e];
}

// ---------------- prep: weight packing + g zero (one launch) ----------------
// blocks 0..3: W1 swizzle; 4..67: W2/W3 swizzle; 68..1067: zero gbuf
__global__ __launch_bounds__(256) void prep(const float* __restrict__ W1, const float* __restrict__ W2,
                                            const float* __restrict__ W3, u16* __restrict__ Wsw1,
                                            u16* __restrict__ Wsw2, u16* __restrict__ Wsw3,
                                            float* __restrict__ gbuf) {
    int bid = blockIdx.x;
    if (bid < 4) {
        // W1 [256 out][8 in] -> B-frag order for one 16x16x32 MFMA (k 8..31 zero)
        int t = bid * 256 + threadIdx.x;  // 1024
        int lane = t & 63;
        int nt = t >> 6;
        int n = nt * 16 + (lane & 15);
        int g = lane >> 4;
        u16 v[8];
#pragma unroll
        for (int j = 0; j < 8; j++) v[j] = (g == 0) ? f2b(W1[n * 8 + j]) : (u16)0;
        ushort4* o = (ushort4*)&Wsw1[(size_t)t * 8];
        o[0] = make_ushort4(v[0], v[1], v[2], v[3]);
        o[1] = make_ushort4(v[4], v[5], v[6], v[7]);
    } else if (bid < 68) {
        int t = (bid - 4) * 256 + threadIdx.x;  // 16384
        const float* W = (t < 8192) ? W2 : W3;
        u16* Wsw = (t < 8192) ? Wsw2 : Wsw3;
        int tl = t & 8191;
        int lane = tl & 63;
        int n = ((tl >> 9) << 4) + (lane & 15);
        int k0 = (((tl >> 6) & 7) << 5) + ((lane >> 4) << 3);
        u16 v[8];
#pragma unroll
        for (int j = 0; j < 8; j++) v[j] = f2b(W[(size_t)n * 256 + k0 + j]);
        ushort4* o = (ushort4*)&Wsw[(size_t)tl * 8];
        o[0] = make_ushort4(v[0], v[1], v[2], v[3]);
        o[1] = make_ushort4(v[4], v[5], v[6], v[7]);
    } else {
        int i = (bid - 68) * 256 + threadIdx.x;  // 256000 float4
        if (i < (N_GRAPHS * EMB) / 4)
            ((float4*)gbuf)[i] = make_float4(0.f, 0.f, 0.f, 0.f);
    }
}

// ---------------- emb: h0 = bf16(x @ We.T)  [N,8] ----------------
__global__ __launch_bounds__(256) void emb8(const float* __restrict__ x, const float* __restrict__ We,
                                            u16* __restrict__ h0, int n) {
    __shared__ float ws[IN_CH * D_N];
    int tid = threadIdx.x;
    for (int i = tid; i < IN_CH * D_N; i += 256) ws[i] = We[i];
    __syncthreads();
    int node = blockIdx.x * 256 + tid;
    if (node >= n) return;
    float xr[D_N];
    const float* xp = &x[(size_t)node * D_N];
#pragma unroll
    for (int k = 0; k < D_N; k++) xr[k] = xp[k];
    ushort8 o;
#pragma unroll
    for (int j = 0; j < IN_CH; j++) {
        float acc = 0.f;
#pragma unroll
        for (int k = 0; k < D_N; k++) acc += xr[k] * ws[j * D_N + k];
        o[j] = f2b(acc);
    }
    *(ushort8*)&h0[(size_t)node * IN_CH] = o;
}

// ---------------- fused layer 1: agg8 + MFMA GEMM (8->256) ----------------
// Merged edge stream: 16 edges in flight, 4 lanes/edge; per-lane routing.
__global__ __launch_bounds__(256) void fused_l1(const u16* __restrict__ h0,
                                                const int* __restrict__ rowptr,
                                                const int* __restrict__ csr,
                                                const u16* __restrict__ Wsw1,
                                                const float* __restrict__ bias,
                                                u16* __restrict__ Hout) {
    __shared__ __attribute__((aligned(16))) u16 lds[16][256];  // 8 KB
    const int wid = threadIdx.x >> 6;
    const int lane = threadIdx.x & 63;
    const int row0 = blockIdx.x * 16;
    char* ldsb = (char*)lds;
    const char* h0c = (const char*)h0;

    // ---- phase 1: merged gather over rows rbase..rbase+3 ----
    const int eslot = lane >> 2;       // edge slot 0..15
    const int c4 = (lane & 3) * 4;     // byte offset of lane's 2 channels
    const int rbase = row0 + wid * 4;
    int s0 = RFL(rowptr[rbase + 0]);
    int t0 = RFL(rowptr[rbase + 1]);
    int t1 = RFL(rowptr[rbase + 2]);
    int t2 = RFL(rowptr[rbase + 3]);
    int t3 = RFL(rowptr[rbase + 4]);

    f32x2 a0 = {0.f, 0.f}, a1 = {0.f, 0.f}, a2 = {0.f, 0.f}, a3 = {0.f, 0.f};
    int ee = s0;
    int ce0 = ee + eslot;
    if (ce0 > t3 - 1) ce0 = t3 - 1;
    if (ce0 < 0) ce0 = 0;
    int idxv = csr[ce0];
    while (ee < t3) {
        int ed = ee + eslot;
        unsigned v = *(const unsigned*)(h0c + (size_t)idxv * 16 + c4);
        int ce = ed + 16;
        if (ce > t3 - 1) ce = t3 - 1;
        if (ce < 0) ce = 0;
        int nidx = csr[ce];
        f32x2 u = unpk(v);
        bool b0 = ed < t0, b1 = ed < t1, b2 = ed < t2, b3 = ed < t3;
        if (b0) a0 += u;
        else if (b1) a1 += u;
        else if (b2) a2 += u;
        else if (b3) a3 += u;
        idxv = nidx;
        ee += 16;
    }
    // butterfly over eslot bits (lane bits 2..5)
#pragma unroll
    for (int off = 4; off <= 32; off <<= 1) {
        a0[0] += __shfl_xor(a0[0], off, 64); a0[1] += __shfl_xor(a0[1], off, 64);
        a1[0] += __shfl_xor(a1[0], off, 64); a1[1] += __shfl_xor(a1[1], off, 64);
        a2[0] += __shfl_xor(a2[0], off, 64); a2[1] += __shfl_xor(a2[1], off, 64);
        a3[0] += __shfl_xor(a3[0], off, 64); a3[1] += __shfl_xor(a3[1], off, 64);
    }
    if (eslot == 0)      *(unsigned*)(ldsb + (wid * 4 + 0) * 16 + c4) = pk2(a0);
    else if (eslot == 1) *(unsigned*)(ldsb + (wid * 4 + 1) * 16 + c4) = pk2(a1);
    else if (eslot == 2) *(unsigned*)(ldsb + (wid * 4 + 2) * 16 + c4) = pk2(a2);
    else if (eslot == 3) *(unsigned*)(ldsb + (wid * 4 + 3) * 16 + c4) = pk2(a3);
    __syncthreads();

    // ---- phase 2: A fragment (K=32: k<8 real, rest zero) ----
    const int m = lane & 15;
    const int g = lane >> 4;
    bf16x8 a = {};
    if (g == 0) a = *(const bf16x8*)(ldsb + m * 16);
    __syncthreads();

    // ---- phase 3: 1 MFMA per col-tile ----
    f32x4 acc[4];
#pragma unroll
    for (int t = 0; t < 4; t++) acc[t] = (f32x4){0.f, 0.f, 0.f, 0.f};
    const bf16x8* wp = (const bf16x8*)Wsw1 + lane;
#pragma unroll
    for (int t = 0; t < 4; t++) {
        bf16x8 b = wp[(wid * 4 + t) * 64];
        acc[t] = __builtin_amdgcn_mfma_f32_16x16x32_bf16(a, b, acc[t], 0, 0, 0);
    }

    // ---- phase 4: C -> LDS (bf16, swizzled [16][512B]) ----
#pragma unroll
    for (int t = 0; t < 4; t++) {
        int col = (wid * 4 + t) * 16 + m;
#pragma unroll
        for (int r = 0; r < 4; r++) {
            int row = g * 4 + r;
            *(u16*)(ldsb + row * 512 + ((col * 2) ^ ((row & 7) << 4))) = f2b(acc[t][r]);
        }
    }
    __syncthreads();

    // ---- phase 5: epilogue relu + bias ----
    {
        int row = threadIdx.x >> 4;
        int cb0 = (threadIdx.x & 15) * 16;
#pragma unroll
        for (int p = 0; p < 2; p++) {
            int cb = cb0 + p * 256;
            ushort8 c = *(const ushort8*)(ldsb + row * 512 + (cb ^ ((row & 7) << 4)));
            int gcol = cb >> 1;
            size_t gidx = (size_t)(row0 + row) * EMB + gcol;
            float4 bq0 = *(const float4*)&bias[gcol];
            float4 bq1 = *(const float4*)&bias[gcol + 4];
            float bb[8] = {bq0.x, bq0.y, bq0.z, bq0.w, bq1.x, bq1.y, bq1.z, bq1.w};
            ushort8 o;
#pragma unroll
            for (int j = 0; j < 8; j++)
                o[j] = f2b(fmaxf(b2f(c[j]) + bb[j], 0.f));
            *(ushort8*)&Hout[gidx] = o;
        }
    }
}

// ---------------- fused GCN layer 2 ----------------
__global__ __launch_bounds__(256, 8) void fused_gcn(const u16* __restrict__ Hin,
                                                    const int* __restrict__ rowptr,
                                                    const int* __restrict__ csr,
                                                    const u16* __restrict__ Wsw,
                                                    const float* __restrict__ bias,
                                                    u16* __restrict__ Hout) {
    __shared__ __attribute__((aligned(16))) u16 lds[16][256];  // 8 KB
    const int wid = threadIdx.x >> 6;
    const int lane = threadIdx.x & 63;
    const int row0 = blockIdx.x * 16;
    char* ldsb = (char*)lds;
    const char* hbase = (const char*)Hin;
    const int laneByte = lane * 8;

    // ---- phase 1: merged-stream gather, depth 12 ----
    const int rbase = row0 + wid * 4;
    int s0 = RFL(rowptr[rbase + 0]);
    int t0 = RFL(rowptr[rbase + 1]);
    int t1 = RFL(rowptr[rbase + 2]);
    int t2 = RFL(rowptr[rbase + 3]);
    int t3 = RFL(rowptr[rbase + 4]);

    f32x2 r0a = {0.f, 0.f}, r0b = {0.f, 0.f};
    f32x2 r1a = {0.f, 0.f}, r1b = {0.f, 0.f};
    f32x2 r2a = {0.f, 0.f}, r2b = {0.f, 0.f};
    f32x2 r3a = {0.f, 0.f}, r3b = {0.f, 0.f};

    int idx[12];
#pragma unroll
    for (int d = 0; d < 12; d++) {
        int ce = s0 + d;
        if (ce > t3 - 1) ce = t3 - 1;
        if (ce < 0) ce = 0;
        idx[d] = RFL(csr[ce]);
    }
    int ee = s0;
    while (ee < t3) {
        uint2 v[12];
#pragma unroll
        for (int d = 0; d < 12; d++)
            v[d] = *(const uint2*)(hbase + (size_t)idx[d] * (EMB * 2) + laneByte);
        int eb = ee;
        ee += 12;
#pragma unroll
        for (int d = 0; d < 12; d++) {
            int ce = ee + d;
            if (ce > t3 - 1) ce = t3 - 1;
            if (ce < 0) ce = 0;
            idx[d] = RFL(csr[ce]);
        }
#pragma unroll
        for (int d = 0; d < 12; d++) {
            int ed = eb + d;
            if (ed < t3) {  // wave-uniform
                f32x2 ux = unpk(v[d].x), uy = unpk(v[d].y);
                if (ed < t0)      { r0a += ux; r0b += uy; }
                else if (ed < t1) { r1a += ux; r1b += uy; }
                else if (ed < t2) { r2a += ux; r2b += uy; }
                else              { r3a += ux; r3b += uy; }
            }
        }
    }

    {
        f32x2 lo[4] = {r0a, r1a, r2a, r3a};
        f32x2 hi[4] = {r0b, r1b, r2b, r3b};
#pragma unroll
        for (int r = 0; r < 4; r++) {
            int li = wid * 4 + r;
            *(uint2*)(ldsb + li * 512 + (laneByte ^ ((li & 7) << 4))) = make_uint2(pk2(lo[r]), pk2(hi[r]));
        }
    }
    __syncthreads();

    // ---- phase 2: A fragments ----
    const int m = lane & 15;
    const int g = lane >> 4;
    bf16x8 a[8];
#pragma unroll
    for (int ks = 0; ks < 8; ks++) {
        int boff = (g * 16 + ks * 64) ^ ((m & 7) << 4);
        a[ks] = *(const bf16x8*)(ldsb + m * 512 + boff);
    }
    __syncthreads();

    // ---- phase 3: MFMA ----
    f32x4 acc2[4];
#pragma unroll
    for (int t = 0; t < 4; t++) acc2[t] = (f32x4){0.f, 0.f, 0.f, 0.f};
    const bf16x8* wp = (const bf16x8*)Wsw + lane;
#pragma unroll
    for (int t = 0; t < 4; t++) {
        int nt = wid * 4 + t;
        bf16x8 b[8];
#pragma unroll
        for (int ks = 0; ks < 8; ks++) b[ks] = wp[(nt * 8 + ks) * 64];
#pragma unroll
        for (int ks = 0; ks < 8; ks++)
            acc2[t] = __builtin_amdgcn_mfma_f32_16x16x32_bf16(a[ks], b[ks], acc2[t], 0, 0, 0);
    }

    // ---- phase 4: C -> LDS (bf16, swizzled) ----
#pragma unroll
    for (int t = 0; t < 4; t++) {
        int col = (wid * 4 + t) * 16 + m;
#pragma unroll
        for (int r = 0; r < 4; r++) {
            int row = g * 4 + r;
            *(u16*)(ldsb + row * 512 + ((col * 2) ^ ((row & 7) << 4))) = f2b(acc2[t][r]);
        }
    }
    __syncthreads();

    // ---- phase 5: epilogue relu + bias + residual ----
    {
        int row = threadIdx.x >> 4;
        int cb0 = (threadIdx.x & 15) * 16;
#pragma unroll
        for (int p = 0; p < 2; p++) {
            int cb = cb0 + p * 256;
            ushort8 c = *(const ushort8*)(ldsb + row * 512 + (cb ^ ((row & 7) << 4)));
            int gcol = cb >> 1;
            size_t gidx = (size_t)(row0 + row) * EMB + gcol;
            ushort8 hres = *(const ushort8*)&Hin[gidx];
            float4 bq0 = *(const float4*)&bias[gcol];
            float4 bq1 = *(const float4*)&bias[gcol + 4];
            float bb[8] = {bq0.x, bq0.y, bq0.z, bq0.w, bq1.x, bq1.y, bq1.z, bq1.w};
            ushort8 o;
#pragma unroll
            for (int j = 0; j < 8; j++)
                o[j] = f2b(fmaxf(b2f(c[j]) + bb[j], 0.f) + b2f(hres[j]));
            *(ushort8*)&Hout[gidx] = o;
        }
    }
}

// ---------------- fused GCN layer 3 + pooling ----------------
__global__ __launch_bounds__(256, 8) void fused_gcn_pool(const u16* __restrict__ Hin,
                                                         const int* __restrict__ rowptr,
                                                         const int* __restrict__ csr,
                                                         const u16* __restrict__ Wsw,
                                                         const float* __restrict__ bias,
                                                         const int* __restrict__ seg,
                                                         float* __restrict__ g) {
    __shared__ __attribute__((aligned(16))) u16 lds[16][256];  // 8 KB
    __shared__ int segs[16];
    const int wid = threadIdx.x >> 6;
    const int lane = threadIdx.x & 63;
    const int row0 = blockIdx.x * 16;
    char* ldsb = (char*)lds;
    const char* hbase = (const char*)Hin;
    const int laneByte = lane * 8;

    const int rbase = row0 + wid * 4;
    int s0 = RFL(rowptr[rbase + 0]);
    int t0 = RFL(rowptr[rbase + 1]);
    int t1 = RFL(rowptr[rbase + 2]);
    int t2 = RFL(rowptr[rbase + 3]);
    int t3 = RFL(rowptr[rbase + 4]);

    f32x2 r0a = {0.f, 0.f}, r0b = {0.f, 0.f};
    f32x2 r1a = {0.f, 0.f}, r1b = {0.f, 0.f};
    f32x2 r2a = {0.f, 0.f}, r2b = {0.f, 0.f};
    f32x2 r3a = {0.f, 0.f}, r3b = {0.f, 0.f};

    int idx[12];
#pragma unroll
    for (int d = 0; d < 12; d++) {
        int ce = s0 + d;
        if (ce > t3 - 1) ce = t3 - 1;
        if (ce < 0) ce = 0;
        idx[d] = RFL(csr[ce]);
    }
    int ee = s0;
    while (ee < t3) {
        uint2 v[12];
#pragma unroll
        for (int d = 0; d < 12; d++)
            v[d] = *(const uint2*)(hbase + (size_t)idx[d] * (EMB * 2) + laneByte);
        int eb = ee;
        ee += 12;
#pragma unroll
        for (int d = 0; d < 12; d++) {
            int ce = ee + d;
            if (ce > t3 - 1) ce = t3 - 1;
            if (ce < 0) ce = 0;
            idx[d] = RFL(csr[ce]);
        }
#pragma unroll
        for (int d = 0; d < 12; d++) {
            int ed = eb + d;
            if (ed < t3) {
                f32x2 ux = unpk(v[d].x), uy = unpk(v[d].y);
                if (ed < t0)      { r0a += ux; r0b += uy; }
                else if (ed < t1) { r1a += ux; r1b += uy; }
                else if (ed < t2) { r2a += ux; r2b += uy; }
                else              { r3a += ux; r3b += uy; }
            }
        }
    }

    {
        f32x2 lo[4] = {r0a, r1a, r2a, r3a};
        f32x2 hi[4] = {r0b, r1b, r2b, r3b};
#pragma unroll
        for (int r = 0; r < 4; r++) {
            int li = wid * 4 + r;
            *(uint2*)(ldsb + li * 512 + (laneByte ^ ((li & 7) << 4))) = make_uint2(pk2(lo[r]), pk2(hi[r]));
        }
    }
    if (threadIdx.x < 16) segs[threadIdx.x] = seg[row0 + threadIdx.x];
    __syncthreads();

    // ---- phase 2: A fragments ----
    const int m = lane & 15;
    const int g_ = lane >> 4;
    bf16x8 a[8];
#pragma unroll
    for (int ks = 0; ks < 8; ks++) {
        int boff = (g_ * 16 + ks * 64) ^ ((m & 7) << 4);
        a[ks] = *(const bf16x8*)(ldsb + m * 512 + boff);
    }
    __syncthreads();

    // ---- phase 3: MFMA ----
    f32x4 acc2[4];
#pragma unroll
    for (int t = 0; t < 4; t++) acc2[t] = (f32x4){0.f, 0.f, 0.f, 0.f};
    const bf16x8* wp = (const bf16x8*)Wsw + lane;
#pragma unroll
    for (int t = 0; t < 4; t++) {
        int nt = wid * 4 + t;
        bf16x8 b[8];
#pragma unroll
        for (int ks = 0; ks < 8; ks++) b[ks] = wp[(nt * 8 + ks) * 64];
#pragma unroll
        for (int ks = 0; ks < 8; ks++)
            acc2[t] = __builtin_amdgcn_mfma_f32_16x16x32_bf16(a[ks], b[ks], acc2[t], 0, 0, 0);
    }

    // ---- phase 4: C -> LDS (bf16, swizzled) ----
#pragma unroll
    for (int t = 0; t < 4; t++) {
        int col = (wid * 4 + t) * 16 + m;
#pragma unroll
        for (int r = 0; r < 4; r++) {
            int row = g_ * 4 + r;
            *(u16*)(ldsb + row * 512 + ((col * 2) ^ ((row & 7) << 4))) = f2b(acc2[t][r]);
        }
    }
    __syncthreads();

    // ---- phase 5: final values (relu+bias+residual) back into LDS ----
    {
        int row = threadIdx.x >> 4;
        int cb0 = (threadIdx.x & 15) * 16;
#pragma unroll
        for (int p = 0; p < 2; p++) {
            int cb = cb0 + p * 256;
            char* lp = ldsb + row * 512 + (cb ^ ((row & 7) << 4));
            ushort8 c = *(const ushort8*)lp;
            int gcol = cb >> 1;
            size_t gidx = (size_t)(row0 + row) * EMB + gcol;
            ushort8 hres = *(const ushort8*)&Hin[gidx];
            float4 bq0 = *(const float4*)&bias[gcol];
            float4 bq1 = *(const float4*)&bias[gcol + 4];
            float bb[8] = {bq0.x, bq0.y, bq0.z, bq0.w, bq1.x, bq1.y, bq1.z, bq1.w};
            ushort8 o;
#pragma unroll
            for (int j = 0; j < 8; j++)
                o[j] = f2b(fmaxf(b2f(c[j]) + bb[j], 0.f) + b2f(hres[j]));
            *(ushort8*)lp = o;
        }
    }
    __syncthreads();

    // ---- phase 6: segment-sum the 16 rows into g (thread = channel) ----
    {
        int ch = threadIdx.x;
        float acc = 0.f;
        int gprev = segs[0];
#pragma unroll
        for (int r = 0; r < 16; r++) {
            int gr = segs[r];  // block-uniform
            float v = b2f(*(const u16*)(ldsb + r * 512 + ((ch * 2) ^ ((r & 7) << 4))));
            if (gr != gprev) {
                atomicAdd(&g[(size_t)gprev * EMB + ch], acc);
                acc = 0.f;
                gprev = gr;
            }
            acc += v;
        }
        atomicAdd(&g[(size_t)gprev * EMB + ch], acc);
    }
}

// ---------------- head: 4 graphs per block (Wp1 read shared 4x) ----------------
__global__ __launch_bounds__(256) void head4(const float* __restrict__ g, const float* __restrict__ Wp1,
                                             const float* __restrict__ Wp2, const float* __restrict__ bp2,
                                             float* __restrict__ out) {
    __shared__ float gsm[4][EMB];
    __shared__ float red[4][128];
    int b0 = blockIdx.x * 4;
    int t = threadIdx.x;
    int wid = t >> 6, lane = t & 63;
#pragma unroll
    for (int i = 0; i < 4; i++) gsm[i][t] = g[(size_t)(b0 + i) * EMB + t];
    __syncthreads();
    int row = wid * 32 + (lane & 31);
    int half = lane >> 5;
    const float* wr = &Wp1[(size_t)row * EMB + half * 128];
    const float* g0 = &gsm[0][half * 128];
    const float* g1 = &gsm[1][half * 128];
    const float* g2 = &gsm[2][half * 128];
    const float* g3 = &gsm[3][half * 128];
    float d0 = 0.f, d1 = 0.f, d2 = 0.f, d3 = 0.f;
#pragma unroll 4
    for (int k = 0; k < 128; k++) {
        float w = wr[k];
        d0 += w * g0[k]; d1 += w * g1[k]; d2 += w * g2[k]; d3 += w * g3[k];
    }
    d0 += __shfl_xor(d0, 32, 64);
    d1 += __shfl_xor(d1, 32, 64);
    d2 += __shfl_xor(d2, 32, 64);
    d3 += __shfl_xor(d3, 32, 64);
    if (half == 0) {
        float w2 = Wp2[row];
        red[0][row] = fmaxf(d0, 0.f) * w2;
        red[1][row] = fmaxf(d1, 0.f) * w2;
        red[2][row] = fmaxf(d2, 0.f) * w2;
        red[3][row] = fmaxf(d3, 0.f) * w2;
    }
    __syncthreads();
    int gi = t >> 6, j = t & 63;
    red[gi][j] += red[gi][j + 64];
    __syncthreads();
    for (int off = 32; off > 0; off >>= 1) {
        if (j < off) red[gi][j] += red[gi][j + off];
        __syncthreads();
    }
    if (j == 0) out[b0 + gi] = red[gi][0] + bp2[0];
}

// ---------------- launch ----------------

extern "C" void kernel_launch(void* const* d_in, const int* in_sizes, int n_in,
                              void* d_out, int out_size, void* d_ws, size_t ws_size,
                              hipStream_t stream) {
    const float* x    = (const float*)d_in[0];
    const int*   src  = (const int*)d_in[1];
    const int*   dst  = (const int*)d_in[2];
    const int*   seg  = (const int*)d_in[3];
    const float* W_emb= (const float*)d_in[4];
    const float* W1   = (const float*)d_in[5];
    const float* b1   = (const float*)d_in[6];
    const float* W2   = (const float*)d_in[7];
    const float* b2   = (const float*)d_in[8];
    const float* W3   = (const float*)d_in[9];
    const float* b3   = (const float*)d_in[10];
    const float* Wp1  = (const float*)d_in[11];
    const float* Wp2  = (const float*)d_in[12];
    const float* bp2  = (const float*)d_in[13];
    float* out = (float*)d_out;

    char* ws = (char*)d_ws;
    size_t off = 0;
    auto alloc = [&](size_t bytes) -> void* {
        void* p = ws + off;
        off = (off + bytes + 255) & ~(size_t)255;
        return p;
    };
    const int N = N_NODES, E = N_EDGES, G = N_GRAPHS;
    u16* hA     = (u16*)alloc((size_t)N * EMB * 2);
    u16* hB     = (u16*)alloc((size_t)N * EMB * 2);
    u16* h0     = (u16*)alloc((size_t)N * IN_CH * 2);
    u16* Wsw1   = (u16*)alloc(16 * 64 * 8 * 2);
    u16* Wsw2   = (u16*)alloc(256 * 256 * 2);
    u16* Wsw3   = (u16*)alloc(256 * 256 * 2);
    int* rowptr = (int*)alloc((size_t)(N + 1) * 4);
    int* deg    = (int*)alloc((size_t)N * 4);
    int* csr    = (int*)alloc((size_t)E * 4);
    int* partials = (int*)alloc(1024 * 4);
    float* gbuf = (float*)alloc((size_t)G * EMB * 4);

    if (off > ws_size) return;  // clean failure instead of OOB crash

    // CSR build (by dst)
    hipMemsetAsync(deg, 0, (size_t)N * 4, stream);
    count_deg<<<E / 256, 256, 0, stream>>>(dst, deg, E);
    scan_a<<<196, 256, 0, stream>>>(deg, rowptr + 1, partials, N);
    scan_b<<<1, 256, 0, stream>>>(partials, 196);
    scan_c<<<782, 256, 0, stream>>>(rowptr, partials, N);
    fill_csr<<<E / 256, 256, 0, stream>>>(src, dst, rowptr, deg, csr, E);

    // weight packing + g zero (single launch)
    prep<<<1068, 256, 0, stream>>>(W1, W2, W3, Wsw1, Wsw2, Wsw3, gbuf);

    // layer 1: h0 = bf16(x @ We.T); hA = relu(agg(h0) @ W1.T + b1)
    emb8<<<782, 256, 0, stream>>>(x, W_emb, h0, N);
    fused_l1<<<N / 16, 256, 0, stream>>>(h0, rowptr, csr, Wsw1, b1, hA);

    // layer 2: hB = relu(agg(hA) @ W2.T + b2) + hA
    fused_gcn<<<N / 16, 256, 0, stream>>>(hA, rowptr, csr, Wsw2, b2, hB);
    // layer 3 + pooling: g += segsum( relu(agg(hB) @ W3.T + b3) + hB )
    fused_gcn_pool<<<N / 16, 256, 0, stream>>>(hB, rowptr, csr, Wsw3, b3, seg, gbuf);

    // head
    head4<<<G / 4, 256, 0, stream>>>(gbuf, Wp1, Wp2, bp2, out);
}

// Round 13
// 384.609 us; speedup vs baseline: 1.2104x; 1.0303x over previous
//
#include <hip/hip_runtime.h>
#include <hip/hip_bf16.h>

#define N_NODES 200000
#define N_EDGES 800000
#define N_GRAPHS 4000
#define D_N 35
#define IN_CH 8
#define EMB 256
#define HID 128

typedef unsigned short u16;
typedef __attribute__((ext_vector_type(8))) short bf16x8;
typedef __attribute__((ext_vector_type(8))) unsigned short ushort8;
typedef __attribute__((ext_vector_type(4))) float f32x4;
typedef __attribute__((ext_vector_type(2))) float f32x2;

__device__ __forceinline__ float b2f(u16 u) {
    union { float f; unsigned v; } x; x.v = ((unsigned)u) << 16; return x.f;
}
__device__ __forceinline__ u16 f2b(float f) {
    union { float f; unsigned v; } x; x.f = f;
    unsigned r = x.v + 0x7fff + ((x.v >> 16) & 1);  // round-nearest-even
    return (u16)(r >> 16);
}
// unpack u32 (2 bf16) -> f32x2 {lo, hi}
__device__ __forceinline__ f32x2 unpk(unsigned u) {
    union { unsigned v[2]; f32x2 f; } r;
    r.v[0] = u << 16; r.v[1] = u & 0xffff0000u;
    return r.f;
}
__device__ __forceinline__ unsigned pk2(f32x2 a) {
    return (unsigned)f2b(a[0]) | ((unsigned)f2b(a[1]) << 16);
}
#define RFL(v) __builtin_amdgcn_readfirstlane(v)

// ---------------- CSR build ----------------

__global__ void count_deg(const int* __restrict__ dst, int* __restrict__ deg, int n) {
    int e = blockIdx.x * 256 + threadIdx.x;
    if (e < n) atomicAdd(&deg[dst[e]], 1);
}

__global__ __launch_bounds__(256) void scan_a(const int* __restrict__ deg, int* __restrict__ incl1,
                                              int* __restrict__ partials, int n) {
    __shared__ int s[256];
    int tid = threadIdx.x;
    int base = blockIdx.x * 1024;
    int v[4]; int sum = 0;
#pragma unroll
    for (int j = 0; j < 4; j++) {
        int idx = base + tid * 4 + j;
        v[j] = (idx < n) ? deg[idx] : 0;
        sum += v[j];
    }
    s[tid] = sum; __syncthreads();
    for (int off = 1; off < 256; off <<= 1) {
        int t = (tid >= off) ? s[tid - off] : 0;
        __syncthreads();
        s[tid] += t;
        __syncthreads();
    }
    int run = s[tid] - sum;
#pragma unroll
    for (int j = 0; j < 4; j++) {
        int idx = base + tid * 4 + j;
        run += v[j];
        if (idx < n) incl1[idx] = run;
    }
    if (tid == 255) partials[blockIdx.x] = s[255];
}

__global__ __launch_bounds__(256) void scan_b(int* __restrict__ partials, int np) {
    __shared__ int s[256];
    int tid = threadIdx.x;
    int v = (tid < np) ? partials[tid] : 0;
    s[tid] = v; __syncthreads();
    for (int off = 1; off < 256; off <<= 1) {
        int t = (tid >= off) ? s[tid - off] : 0;
        __syncthreads();
        s[tid] += t;
        __syncthreads();
    }
    if (tid < np) partials[tid] = s[tid] - v;
}

__global__ void scan_c(int* __restrict__ rowptr, const int* __restrict__ partials, int n) {
    int i = blockIdx.x * 256 + threadIdx.x;
    if (i < n) rowptr[1 + i] += partials[i >> 10];
    if (i == 0) rowptr[0] = 0;
}

// slot-allocate by atomicSub on counts (intra-row order nondeterministic, sum unchanged)
__global__ void fill_csr(const int* __restrict__ src, const int* __restrict__ dst,
                         const int* __restrict__ rowptr, int* __restrict__ cnt,
                         int* __restrict__ csr, int n) {
    int e = blockIdx.x * 256 + threadIdx.x;
    if (e >= n) return;
    int d = dst[e];
    int p = atomicSub(&cnt[d], 1) - 1;
    csr[rowptr[d] + p] = src[e];
}

// ---------------- prep: weight packing + g zero (one launch) ----------------
__global__ __launch_bounds__(256) void prep(const float* __restrict__ W1, const float* __restrict__ W2,
                                            const float* __restrict__ W3, u16* __restrict__ Wsw1,
                                            u16* __restrict__ Wsw2, u16* __restrict__ Wsw3,
                                            float* __restrict__ gbuf) {
    int bid = blockIdx.x;
    if (bid < 4) {
        int t = bid * 256 + threadIdx.x;  // 1024
        int lane = t & 63;
        int nt = t >> 6;
        int n = nt * 16 + (lane & 15);
        int g = lane >> 4;
        u16 v[8];
#pragma unroll
        for (int j = 0; j < 8; j++) v[j] = (g == 0) ? f2b(W1[n * 8 + j]) : (u16)0;
        ushort4* o = (ushort4*)&Wsw1[(size_t)t * 8];
        o[0] = make_ushort4(v[0], v[1], v[2], v[3]);
        o[1] = make_ushort4(v[4], v[5], v[6], v[7]);
    } else if (bid < 68) {
        int t = (bid - 4) * 256 + threadIdx.x;  // 16384
        const float* W = (t < 8192) ? W2 : W3;
        u16* Wsw = (t < 8192) ? Wsw2 : Wsw3;
        int tl = t & 8191;
        int lane = tl & 63;
        int n = ((tl >> 9) << 4) + (lane & 15);
        int k0 = (((tl >> 6) & 7) << 5) + ((lane >> 4) << 3);
        u16 v[8];
#pragma unroll
        for (int j = 0; j < 8; j++) v[j] = f2b(W[(size_t)n * 256 + k0 + j]);
        ushort4* o = (ushort4*)&Wsw[(size_t)tl * 8];
        o[0] = make_ushort4(v[0], v[1], v[2], v[3]);
        o[1] = make_ushort4(v[4], v[5], v[6], v[7]);
    } else {
        int i = (bid - 68) * 256 + threadIdx.x;  // 256000 float4
        if (i < (N_GRAPHS * EMB) / 4)
            ((float4*)gbuf)[i] = make_float4(0.f, 0.f, 0.f, 0.f);
    }
}

// ---------------- emb: h0 = bf16(x @ We.T)  [N,8] ----------------
__global__ __launch_bounds__(256) void emb8(const float* __restrict__ x, const float* __restrict__ We,
                                            u16* __restrict__ h0, int n) {
    __shared__ float ws[IN_CH * D_N];
    int tid = threadIdx.x;
    for (int i = tid; i < IN_CH * D_N; i += 256) ws[i] = We[i];
    __syncthreads();
    int node = blockIdx.x * 256 + tid;
    if (node >= n) return;
    float xr[D_N];
    const float* xp = &x[(size_t)node * D_N];
#pragma unroll
    for (int k = 0; k < D_N; k++) xr[k] = xp[k];
    ushort8 o;
#pragma unroll
    for (int j = 0; j < IN_CH; j++) {
        float acc = 0.f;
#pragma unroll
        for (int k = 0; k < D_N; k++) acc += xr[k] * ws[j * D_N + k];
        o[j] = f2b(acc);
    }
    *(ushort8*)&h0[(size_t)node * IN_CH] = o;
}

// ---------------- fused layer 1: agg8 + MFMA GEMM (8->256) ----------------
__global__ __launch_bounds__(256) void fused_l1(const u16* __restrict__ h0,
                                                const int* __restrict__ rowptr,
                                                const int* __restrict__ csr,
                                                const u16* __restrict__ Wsw1,
                                                const float* __restrict__ bias,
                                                u16* __restrict__ Hout) {
    __shared__ __attribute__((aligned(16))) u16 lds[16][256];  // 8 KB
    const int wid = threadIdx.x >> 6;
    const int lane = threadIdx.x & 63;
    const int row0 = blockIdx.x * 16;
    char* ldsb = (char*)lds;
    const char* h0c = (const char*)h0;

    // ---- phase 1: merged gather over rows rbase..rbase+3 ----
    const int eslot = lane >> 2;       // edge slot 0..15
    const int c4 = (lane & 3) * 4;     // byte offset of lane's 2 channels
    const int rbase = row0 + wid * 4;
    int s0 = RFL(rowptr[rbase + 0]);
    int t0 = RFL(rowptr[rbase + 1]);
    int t1 = RFL(rowptr[rbase + 2]);
    int t2 = RFL(rowptr[rbase + 3]);
    int t3 = RFL(rowptr[rbase + 4]);

    f32x2 a0 = {0.f, 0.f}, a1 = {0.f, 0.f}, a2 = {0.f, 0.f}, a3 = {0.f, 0.f};
    int ee = s0;
    int ce0 = ee + eslot;
    if (ce0 > t3 - 1) ce0 = t3 - 1;
    if (ce0 < 0) ce0 = 0;
    int idxv = csr[ce0];
    while (ee < t3) {
        int ed = ee + eslot;
        unsigned v = *(const unsigned*)(h0c + (size_t)idxv * 16 + c4);
        int ce = ed + 16;
        if (ce > t3 - 1) ce = t3 - 1;
        if (ce < 0) ce = 0;
        int nidx = csr[ce];
        f32x2 u = unpk(v);
        bool b0 = ed < t0, b1 = ed < t1, b2 = ed < t2, b3 = ed < t3;
        if (b0) a0 += u;
        else if (b1) a1 += u;
        else if (b2) a2 += u;
        else if (b3) a3 += u;
        idxv = nidx;
        ee += 16;
    }
#pragma unroll
    for (int off = 4; off <= 32; off <<= 1) {
        a0[0] += __shfl_xor(a0[0], off, 64); a0[1] += __shfl_xor(a0[1], off, 64);
        a1[0] += __shfl_xor(a1[0], off, 64); a1[1] += __shfl_xor(a1[1], off, 64);
        a2[0] += __shfl_xor(a2[0], off, 64); a2[1] += __shfl_xor(a2[1], off, 64);
        a3[0] += __shfl_xor(a3[0], off, 64); a3[1] += __shfl_xor(a3[1], off, 64);
    }
    if (eslot == 0)      *(unsigned*)(ldsb + (wid * 4 + 0) * 16 + c4) = pk2(a0);
    else if (eslot == 1) *(unsigned*)(ldsb + (wid * 4 + 1) * 16 + c4) = pk2(a1);
    else if (eslot == 2) *(unsigned*)(ldsb + (wid * 4 + 2) * 16 + c4) = pk2(a2);
    else if (eslot == 3) *(unsigned*)(ldsb + (wid * 4 + 3) * 16 + c4) = pk2(a3);
    __syncthreads();

    // ---- phase 2: A fragment (K=32: k<8 real, rest zero) ----
    const int m = lane & 15;
    const int g = lane >> 4;
    bf16x8 a = {};
    if (g == 0) a = *(const bf16x8*)(ldsb + m * 16);
    __syncthreads();

    // ---- phase 3: 1 MFMA per col-tile ----
    f32x4 acc[4];
#pragma unroll
    for (int t = 0; t < 4; t++) acc[t] = (f32x4){0.f, 0.f, 0.f, 0.f};
    const bf16x8* wp = (const bf16x8*)Wsw1 + lane;
#pragma unroll
    for (int t = 0; t < 4; t++) {
        bf16x8 b = wp[(wid * 4 + t) * 64];
        acc[t] = __builtin_amdgcn_mfma_f32_16x16x32_bf16(a, b, acc[t], 0, 0, 0);
    }

    // ---- phase 4: C -> LDS (bf16, swizzled [16][512B]) ----
#pragma unroll
    for (int t = 0; t < 4; t++) {
        int col = (wid * 4 + t) * 16 + m;
#pragma unroll
        for (int r = 0; r < 4; r++) {
            int row = g * 4 + r;
            *(u16*)(ldsb + row * 512 + ((col * 2) ^ ((row & 7) << 4))) = f2b(acc[t][r]);
        }
    }
    __syncthreads();

    // ---- phase 5: epilogue relu + bias ----
    {
        int row = threadIdx.x >> 4;
        int cb0 = (threadIdx.x & 15) * 16;
#pragma unroll
        for (int p = 0; p < 2; p++) {
            int cb = cb0 + p * 256;
            ushort8 c = *(const ushort8*)(ldsb + row * 512 + (cb ^ ((row & 7) << 4)));
            int gcol = cb >> 1;
            size_t gidx = (size_t)(row0 + row) * EMB + gcol;
            float4 bq0 = *(const float4*)&bias[gcol];
            float4 bq1 = *(const float4*)&bias[gcol + 4];
            float bb[8] = {bq0.x, bq0.y, bq0.z, bq0.w, bq1.x, bq1.y, bq1.z, bq1.w};
            ushort8 o;
#pragma unroll
            for (int j = 0; j < 8; j++)
                o[j] = f2b(fmaxf(b2f(c[j]) + bb[j], 0.f));
            *(ushort8*)&Hout[gidx] = o;
        }
    }
}

// ---------------- fused GCN layer 2 (gather depth 8) ----------------
__global__ __launch_bounds__(256, 8) void fused_gcn(const u16* __restrict__ Hin,
                                                    const int* __restrict__ rowptr,
                                                    const int* __restrict__ csr,
                                                    const u16* __restrict__ Wsw,
                                                    const float* __restrict__ bias,
                                                    u16* __restrict__ Hout) {
    __shared__ __attribute__((aligned(16))) u16 lds[16][256];  // 8 KB
    const int wid = threadIdx.x >> 6;
    const int lane = threadIdx.x & 63;
    const int row0 = blockIdx.x * 16;
    char* ldsb = (char*)lds;
    const char* hbase = (const char*)Hin;
    const int laneByte = lane * 8;

    const int rbase = row0 + wid * 4;
    int s0 = RFL(rowptr[rbase + 0]);
    int t0 = RFL(rowptr[rbase + 1]);
    int t1 = RFL(rowptr[rbase + 2]);
    int t2 = RFL(rowptr[rbase + 3]);
    int t3 = RFL(rowptr[rbase + 4]);

    f32x2 r0a = {0.f, 0.f}, r0b = {0.f, 0.f};
    f32x2 r1a = {0.f, 0.f}, r1b = {0.f, 0.f};
    f32x2 r2a = {0.f, 0.f}, r2b = {0.f, 0.f};
    f32x2 r3a = {0.f, 0.f}, r3b = {0.f, 0.f};

    int idx[8];
#pragma unroll
    for (int d = 0; d < 8; d++) {
        int ce = s0 + d;
        if (ce > t3 - 1) ce = t3 - 1;
        if (ce < 0) ce = 0;
        idx[d] = RFL(csr[ce]);
    }
    int ee = s0;
    while (ee < t3) {
        uint2 v[8];
#pragma unroll
        for (int d = 0; d < 8; d++)
            v[d] = *(const uint2*)(hbase + (size_t)idx[d] * (EMB * 2) + laneByte);
        int eb = ee;
        ee += 8;
#pragma unroll
        for (int d = 0; d < 8; d++) {
            int ce = ee + d;
            if (ce > t3 - 1) ce = t3 - 1;
            if (ce < 0) ce = 0;
            idx[d] = RFL(csr[ce]);
        }
#pragma unroll
        for (int d = 0; d < 8; d++) {
            int ed = eb + d;
            if (ed < t3) {  // wave-uniform
                f32x2 ux = unpk(v[d].x), uy = unpk(v[d].y);
                if (ed < t0)      { r0a += ux; r0b += uy; }
                else if (ed < t1) { r1a += ux; r1b += uy; }
                else if (ed < t2) { r2a += ux; r2b += uy; }
                else              { r3a += ux; r3b += uy; }
            }
        }
    }

    {
        f32x2 lo[4] = {r0a, r1a, r2a, r3a};
        f32x2 hi[4] = {r0b, r1b, r2b, r3b};
#pragma unroll
        for (int r = 0; r < 4; r++) {
            int li = wid * 4 + r;
            *(uint2*)(ldsb + li * 512 + (laneByte ^ ((li & 7) << 4))) = make_uint2(pk2(lo[r]), pk2(hi[r]));
        }
    }
    __syncthreads();

    // ---- phase 2: A fragments ----
    const int m = lane & 15;
    const int g = lane >> 4;
    bf16x8 a[8];
#pragma unroll
    for (int ks = 0; ks < 8; ks++) {
        int boff = (g * 16 + ks * 64) ^ ((m & 7) << 4);
        a[ks] = *(const bf16x8*)(ldsb + m * 512 + boff);
    }
    __syncthreads();

    // ---- phase 3: MFMA ----
    f32x4 acc2[4];
#pragma unroll
    for (int t = 0; t < 4; t++) acc2[t] = (f32x4){0.f, 0.f, 0.f, 0.f};
    const bf16x8* wp = (const bf16x8*)Wsw + lane;
#pragma unroll
    for (int t = 0; t < 4; t++) {
        int nt = wid * 4 + t;
        bf16x8 b[8];
#pragma unroll
        for (int ks = 0; ks < 8; ks++) b[ks] = wp[(nt * 8 + ks) * 64];
#pragma unroll
        for (int ks = 0; ks < 8; ks++)
            acc2[t] = __builtin_amdgcn_mfma_f32_16x16x32_bf16(a[ks], b[ks], acc2[t], 0, 0, 0);
    }

    // ---- phase 4: C -> LDS (bf16, swizzled) ----
#pragma unroll
    for (int t = 0; t < 4; t++) {
        int col = (wid * 4 + t) * 16 + m;
#pragma unroll
        for (int r = 0; r < 4; r++) {
            int row = g * 4 + r;
            *(u16*)(ldsb + row * 512 + ((col * 2) ^ ((row & 7) << 4))) = f2b(acc2[t][r]);
        }
    }
    __syncthreads();

    // ---- phase 5: epilogue relu + bias + residual ----
    {
        int row = threadIdx.x >> 4;
        int cb0 = (threadIdx.x & 15) * 16;
#pragma unroll
        for (int p = 0; p < 2; p++) {
            int cb = cb0 + p * 256;
            ushort8 c = *(const ushort8*)(ldsb + row * 512 + (cb ^ ((row & 7) << 4)));
            int gcol = cb >> 1;
            size_t gidx = (size_t)(row0 + row) * EMB + gcol;
            ushort8 hres = *(const ushort8*)&Hin[gidx];
            float4 bq0 = *(const float4*)&bias[gcol];
            float4 bq1 = *(const float4*)&bias[gcol + 4];
            float bb[8] = {bq0.x, bq0.y, bq0.z, bq0.w, bq1.x, bq1.y, bq1.z, bq1.w};
            ushort8 o;
#pragma unroll
            for (int j = 0; j < 8; j++)
                o[j] = f2b(fmaxf(b2f(c[j]) + bb[j], 0.f) + b2f(hres[j]));
            *(ushort8*)&Hout[gidx] = o;
        }
    }
}

// ---------------- fused GCN layer 3 + pooling (gather depth 8) ----------------
__global__ __launch_bounds__(256, 8) void fused_gcn_pool(const u16* __restrict__ Hin,
                                                         const int* __restrict__ rowptr,
                                                         const int* __restrict__ csr,
                                                         const u16* __restrict__ Wsw,
                                                         const float* __restrict__ bias,
                                                         const int* __restrict__ seg,
                                                         float* __restrict__ g) {
    __shared__ __attribute__((aligned(16))) u16 lds[16][256];  // 8 KB
    __shared__ int segs[16];
    const int wid = threadIdx.x >> 6;
    const int lane = threadIdx.x & 63;
    const int row0 = blockIdx.x * 16;
    char* ldsb = (char*)lds;
    const char* hbase = (const char*)Hin;
    const int laneByte = lane * 8;

    const int rbase = row0 + wid * 4;
    int s0 = RFL(rowptr[rbase + 0]);
    int t0 = RFL(rowptr[rbase + 1]);
    int t1 = RFL(rowptr[rbase + 2]);
    int t2 = RFL(rowptr[rbase + 3]);
    int t3 = RFL(rowptr[rbase + 4]);

    f32x2 r0a = {0.f, 0.f}, r0b = {0.f, 0.f};
    f32x2 r1a = {0.f, 0.f}, r1b = {0.f, 0.f};
    f32x2 r2a = {0.f, 0.f}, r2b = {0.f, 0.f};
    f32x2 r3a = {0.f, 0.f}, r3b = {0.f, 0.f};

    int idx[8];
#pragma unroll
    for (int d = 0; d < 8; d++) {
        int ce = s0 + d;
        if (ce > t3 - 1) ce = t3 - 1;
        if (ce < 0) ce = 0;
        idx[d] = RFL(csr[ce]);
    }
    int ee = s0;
    while (ee < t3) {
        uint2 v[8];
#pragma unroll
        for (int d = 0; d < 8; d++)
            v[d] = *(const uint2*)(hbase + (size_t)idx[d] * (EMB * 2) + laneByte);
        int eb = ee;
        ee += 8;
#pragma unroll
        for (int d = 0; d < 8; d++) {
            int ce = ee + d;
            if (ce > t3 - 1) ce = t3 - 1;
            if (ce < 0) ce = 0;
            idx[d] = RFL(csr[ce]);
        }
#pragma unroll
        for (int d = 0; d < 8; d++) {
            int ed = eb + d;
            if (ed < t3) {
                f32x2 ux = unpk(v[d].x), uy = unpk(v[d].y);
                if (ed < t0)      { r0a += ux; r0b += uy; }
                else if (ed < t1) { r1a += ux; r1b += uy; }
                else if (ed < t2) { r2a += ux; r2b += uy; }
                else              { r3a += ux; r3b += uy; }
            }
        }
    }

    {
        f32x2 lo[4] = {r0a, r1a, r2a, r3a};
        f32x2 hi[4] = {r0b, r1b, r2b, r3b};
#pragma unroll
        for (int r = 0; r < 4; r++) {
            int li = wid * 4 + r;
            *(uint2*)(ldsb + li * 512 + (laneByte ^ ((li & 7) << 4))) = make_uint2(pk2(lo[r]), pk2(hi[r]));
        }
    }
    if (threadIdx.x < 16) segs[threadIdx.x] = seg[row0 + threadIdx.x];
    __syncthreads();

    // ---- phase 2: A fragments ----
    const int m = lane & 15;
    const int g_ = lane >> 4;
    bf16x8 a[8];
#pragma unroll
    for (int ks = 0; ks < 8; ks++) {
        int boff = (g_ * 16 + ks * 64) ^ ((m & 7) << 4);
        a[ks] = *(const bf16x8*)(ldsb + m * 512 + boff);
    }
    __syncthreads();

    // ---- phase 3: MFMA ----
    f32x4 acc2[4];
#pragma unroll
    for (int t = 0; t < 4; t++) acc2[t] = (f32x4){0.f, 0.f, 0.f, 0.f};
    const bf16x8* wp = (const bf16x8*)Wsw + lane;
#pragma unroll
    for (int t = 0; t < 4; t++) {
        int nt = wid * 4 + t;
        bf16x8 b[8];
#pragma unroll
        for (int ks = 0; ks < 8; ks++) b[ks] = wp[(nt * 8 + ks) * 64];
#pragma unroll
        for (int ks = 0; ks < 8; ks++)
            acc2[t] = __builtin_amdgcn_mfma_f32_16x16x32_bf16(a[ks], b[ks], acc2[t], 0, 0, 0);
    }

    // ---- phase 4: C -> LDS (bf16, swizzled) ----
#pragma unroll
    for (int t = 0; t < 4; t++) {
        int col = (wid * 4 + t) * 16 + m;
#pragma unroll
        for (int r = 0; r < 4; r++) {
            int row = g_ * 4 + r;
            *(u16*)(ldsb + row * 512 + ((col * 2) ^ ((row & 7) << 4))) = f2b(acc2[t][r]);
        }
    }
    __syncthreads();

    // ---- phase 5: final values (relu+bias+residual) back into LDS ----
    {
        int row = threadIdx.x >> 4;
        int cb0 = (threadIdx.x & 15) * 16;
#pragma unroll
        for (int p = 0; p < 2; p++) {
            int cb = cb0 + p * 256;
            char* lp = ldsb + row * 512 + (cb ^ ((row & 7) << 4));
            ushort8 c = *(const ushort8*)lp;
            int gcol = cb >> 1;
            size_t gidx = (size_t)(row0 + row) * EMB + gcol;
            ushort8 hres = *(const ushort8*)&Hin[gidx];
            float4 bq0 = *(const float4*)&bias[gcol];
            float4 bq1 = *(const float4*)&bias[gcol + 4];
            float bb[8] = {bq0.x, bq0.y, bq0.z, bq0.w, bq1.x, bq1.y, bq1.z, bq1.w};
            ushort8 o;
#pragma unroll
            for (int j = 0; j < 8; j++)
                o[j] = f2b(fmaxf(b2f(c[j]) + bb[j], 0.f) + b2f(hres[j]));
            *(ushort8*)lp = o;
        }
    }
    __syncthreads();

    // ---- phase 6: segment-sum the 16 rows into g (thread = channel) ----
    {
        int ch = threadIdx.x;
        float acc = 0.f;
        int gprev = segs[0];
#pragma unroll
        for (int r = 0; r < 16; r++) {
            int gr = segs[r];  // block-uniform
            float v = b2f(*(const u16*)(ldsb + r * 512 + ((ch * 2) ^ ((r & 7) << 4))));
            if (gr != gprev) {
                atomicAdd(&g[(size_t)gprev * EMB + ch], acc);
                acc = 0.f;
                gprev = gr;
            }
            acc += v;
        }
        atomicAdd(&g[(size_t)gprev * EMB + ch], acc);
    }
}

// ---------------- head: 4 graphs per block (Wp1 read shared 4x) ----------------
__global__ __launch_bounds__(256) void head4(const float* __restrict__ g, const float* __restrict__ Wp1,
                                             const float* __restrict__ Wp2, const float* __restrict__ bp2,
                                             float* __restrict__ out) {
    __shared__ float gsm[4][EMB];
    __shared__ float red[4][128];
    int b0 = blockIdx.x * 4;
    int t = threadIdx.x;
    int wid = t >> 6, lane = t & 63;
#pragma unroll
    for (int i = 0; i < 4; i++) gsm[i][t] = g[(size_t)(b0 + i) * EMB + t];
    __syncthreads();
    int row = wid * 32 + (lane & 31);
    int half = lane >> 5;
    const float* wr = &Wp1[(size_t)row * EMB + half * 128];
    const float* g0 = &gsm[0][half * 128];
    const float* g1 = &gsm[1][half * 128];
    const float* g2 = &gsm[2][half * 128];
    const float* g3 = &gsm[3][half * 128];
    float d0 = 0.f, d1 = 0.f, d2 = 0.f, d3 = 0.f;
#pragma unroll 4
    for (int k = 0; k < 128; k++) {
        float w = wr[k];
        d0 += w * g0[k]; d1 += w * g1[k]; d2 += w * g2[k]; d3 += w * g3[k];
    }
    d0 += __shfl_xor(d0, 32, 64);
    d1 += __shfl_xor(d1, 32, 64);
    d2 += __shfl_xor(d2, 32, 64);
    d3 += __shfl_xor(d3, 32, 64);
    if (half == 0) {
        float w2 = Wp2[row];
        red[0][row] = fmaxf(d0, 0.f) * w2;
        red[1][row] = fmaxf(d1, 0.f) * w2;
        red[2][row] = fmaxf(d2, 0.f) * w2;
        red[3][row] = fmaxf(d3, 0.f) * w2;
    }
    __syncthreads();
    int gi = t >> 6, j = t & 63;
    red[gi][j] += red[gi][j + 64];
    __syncthreads();
    for (int off = 32; off > 0; off >>= 1) {
        if (j < off) red[gi][j] += red[gi][j + off];
        __syncthreads();
    }
    if (j == 0) out[b0 + gi] = red[gi][0] + bp2[0];
}

// ---------------- launch ----------------

extern "C" void kernel_launch(void* const* d_in, const int* in_sizes, int n_in,
                              void* d_out, int out_size, void* d_ws, size_t ws_size,
                              hipStream_t stream) {
    const float* x    = (const float*)d_in[0];
    const int*   src  = (const int*)d_in[1];
    const int*   dst  = (const int*)d_in[2];
    const int*   seg  = (const int*)d_in[3];
    const float* W_emb= (const float*)d_in[4];
    const float* W1   = (const float*)d_in[5];
    const float* b1   = (const float*)d_in[6];
    const float* W2   = (const float*)d_in[7];
    const float* b2   = (const float*)d_in[8];
    const float* W3   = (const float*)d_in[9];
    const float* b3   = (const float*)d_in[10];
    const float* Wp1  = (const float*)d_in[11];
    const float* Wp2  = (const float*)d_in[12];
    const float* bp2  = (const float*)d_in[13];
    float* out = (float*)d_out;

    char* ws = (char*)d_ws;
    size_t off = 0;
    auto alloc = [&](size_t bytes) -> void* {
        void* p = ws + off;
        off = (off + bytes + 255) & ~(size_t)255;
        return p;
    };
    const int N = N_NODES, E = N_EDGES, G = N_GRAPHS;
    u16* hA     = (u16*)alloc((size_t)N * EMB * 2);
    u16* hB     = (u16*)alloc((size_t)N * EMB * 2);
    u16* h0     = (u16*)alloc((size_t)N * IN_CH * 2);
    u16* Wsw1   = (u16*)alloc(16 * 64 * 8 * 2);
    u16* Wsw2   = (u16*)alloc(256 * 256 * 2);
    u16* Wsw3   = (u16*)alloc(256 * 256 * 2);
    int* rowptr = (int*)alloc((size_t)(N + 1) * 4);
    int* deg    = (int*)alloc((size_t)N * 4);
    int* csr    = (int*)alloc((size_t)E * 4);
    int* partials = (int*)alloc(1024 * 4);
    float* gbuf = (float*)alloc((size_t)G * EMB * 4);

    if (off > ws_size) return;  // clean failure instead of OOB crash

    // CSR build (by dst)
    hipMemsetAsync(deg, 0, (size_t)N * 4, stream);
    count_deg<<<E / 256, 256, 0, stream>>>(dst, deg, E);
    scan_a<<<196, 256, 0, stream>>>(deg, rowptr + 1, partials, N);
    scan_b<<<1, 256, 0, stream>>>(partials, 196);
    scan_c<<<782, 256, 0, stream>>>(rowptr, partials, N);
    fill_csr<<<E / 256, 256, 0, stream>>>(src, dst, rowptr, deg, csr, E);

    // weight packing + g zero (single launch)
    prep<<<1068, 256, 0, stream>>>(W1, W2, W3, Wsw1, Wsw2, Wsw3, gbuf);

    // layer 1: h0 = bf16(x @ We.T); hA = relu(agg(h0) @ W1.T + b1)
    emb8<<<782, 256, 0, stream>>>(x, W_emb, h0, N);
    fused_l1<<<N / 16, 256, 0, stream>>>(h0, rowptr, csr, Wsw1, b1, hA);

    // layer 2: hB = relu(agg(hA) @ W2.T + b2) + hA
    fused_gcn<<<N / 16, 256, 0, stream>>>(hA, rowptr, csr, Wsw2, b2, hB);
    // layer 3 + pooling: g += segsum( relu(agg(hB) @ W3.T + b3) + hB )
    fused_gcn_pool<<<N / 16, 256, 0, stream>>>(hB, rowptr, csr, Wsw3, b3, seg, gbuf);

    // head
    head4<<<G / 4, 256, 0, stream>>>(gbuf, Wp1, Wp2, bp2, out);
}

// Round 14
// 371.307 us; speedup vs baseline: 1.2537x; 1.0358x over previous
//
#include <hip/hip_runtime.h>
#include <hip/hip_bf16.h>

#define N_NODES 200000
#define N_EDGES 800000
#define N_GRAPHS 4000
#define D_N 35
#define IN_CH 8
#define EMB 256
#define HID 128

typedef unsigned short u16;
typedef __attribute__((ext_vector_type(8))) short bf16x8;
typedef __attribute__((ext_vector_type(8))) unsigned short ushort8;
typedef __attribute__((ext_vector_type(4))) float f32x4;
typedef __attribute__((ext_vector_type(2))) float f32x2;

__device__ __forceinline__ float b2f(u16 u) {
    union { float f; unsigned v; } x; x.v = ((unsigned)u) << 16; return x.f;
}
__device__ __forceinline__ u16 f2b(float f) {
    union { float f; unsigned v; } x; x.f = f;
    unsigned r = x.v + 0x7fff + ((x.v >> 16) & 1);  // round-nearest-even
    return (u16)(r >> 16);
}
// unpack u32 (2 bf16) -> f32x2 {lo, hi}
__device__ __forceinline__ f32x2 unpk(unsigned u) {
    union { unsigned v[2]; f32x2 f; } r;
    r.v[0] = u << 16; r.v[1] = u & 0xffff0000u;
    return r.f;
}
__device__ __forceinline__ unsigned pk2(f32x2 a) {
    return (unsigned)f2b(a[0]) | ((unsigned)f2b(a[1]) << 16);
}
#define RFL(v) __builtin_amdgcn_readfirstlane(v)

// ---------------- merged: emb8 (blocks 0..781) + count_deg (blocks 782..3906) ----------------
__global__ __launch_bounds__(256) void emb_count(const float* __restrict__ x, const float* __restrict__ We,
                                                 u16* __restrict__ h0, const int* __restrict__ dst,
                                                 int* __restrict__ deg) {
    int bid = blockIdx.x;
    if (bid < 782) {
        __shared__ float ws[IN_CH * D_N];
        int tid = threadIdx.x;
        for (int i = tid; i < IN_CH * D_N; i += 256) ws[i] = We[i];
        __syncthreads();
        int node = bid * 256 + tid;
        if (node >= N_NODES) return;
        float xr[D_N];
        const float* xp = &x[(size_t)node * D_N];
#pragma unroll
        for (int k = 0; k < D_N; k++) xr[k] = xp[k];
        ushort8 o;
#pragma unroll
        for (int j = 0; j < IN_CH; j++) {
            float acc = 0.f;
#pragma unroll
            for (int k = 0; k < D_N; k++) acc += xr[k] * ws[j * D_N + k];
            o[j] = f2b(acc);
        }
        *(ushort8*)&h0[(size_t)node * IN_CH] = o;
    } else {
        int e = (bid - 782) * 256 + threadIdx.x;
        if (e < N_EDGES) atomicAdd(&deg[dst[e]], 1);
    }
}

// ---------------- scan ----------------

__global__ __launch_bounds__(256) void scan_a(const int* __restrict__ deg, int* __restrict__ incl1,
                                              int* __restrict__ partials, int n) {
    __shared__ int s[256];
    int tid = threadIdx.x;
    int base = blockIdx.x * 1024;
    int v[4]; int sum = 0;
#pragma unroll
    for (int j = 0; j < 4; j++) {
        int idx = base + tid * 4 + j;
        v[j] = (idx < n) ? deg[idx] : 0;
        sum += v[j];
    }
    s[tid] = sum; __syncthreads();
    for (int off = 1; off < 256; off <<= 1) {
        int t = (tid >= off) ? s[tid - off] : 0;
        __syncthreads();
        s[tid] += t;
        __syncthreads();
    }
    int run = s[tid] - sum;
#pragma unroll
    for (int j = 0; j < 4; j++) {
        int idx = base + tid * 4 + j;
        run += v[j];
        if (idx < n) incl1[idx] = run;
    }
    if (tid == 255) partials[blockIdx.x] = s[255];
}

// merged scan_b + scan_c: each block re-scans the 196 partials in LDS, applies offset.
__global__ __launch_bounds__(256) void scan_bc(int* __restrict__ rowptr, const int* __restrict__ partials, int n) {
    __shared__ int s[256];
    __shared__ int excl[256];
    int tid = threadIdx.x;
    int v = (tid < 196) ? partials[tid] : 0;
    s[tid] = v; __syncthreads();
    for (int off = 1; off < 256; off <<= 1) {
        int t = (tid >= off) ? s[tid - off] : 0;
        __syncthreads();
        s[tid] += t;
        __syncthreads();
    }
    excl[tid] = s[tid] - v;
    __syncthreads();
    int i = blockIdx.x * 256 + tid;
    if (i < n) rowptr[1 + i] += excl[i >> 10];
    if (i == 0) rowptr[0] = 0;
}

// ---------------- merged: fill_csr (blocks 0..3124) + prep (blocks 3125..4192) ----------------
__global__ __launch_bounds__(256) void fill_prep(const int* __restrict__ src, const int* __restrict__ dst,
                                                 const int* __restrict__ rowptr, int* __restrict__ cnt,
                                                 int* __restrict__ csr,
                                                 const float* __restrict__ W1, const float* __restrict__ W2,
                                                 const float* __restrict__ W3, u16* __restrict__ Wsw1,
                                                 u16* __restrict__ Wsw2, u16* __restrict__ Wsw3,
                                                 float* __restrict__ gbuf) {
    int bid = blockIdx.x;
    if (bid < 3125) {
        int e = bid * 256 + threadIdx.x;
        if (e >= N_EDGES) return;
        int d = dst[e];
        int p = atomicSub(&cnt[d], 1) - 1;
        csr[rowptr[d] + p] = src[e];
        return;
    }
    bid -= 3125;
    if (bid < 4) {
        int t = bid * 256 + threadIdx.x;  // 1024
        int lane = t & 63;
        int nt = t >> 6;
        int n = nt * 16 + (lane & 15);
        int g = lane >> 4;
        u16 v[8];
#pragma unroll
        for (int j = 0; j < 8; j++) v[j] = (g == 0) ? f2b(W1[n * 8 + j]) : (u16)0;
        ushort4* o = (ushort4*)&Wsw1[(size_t)t * 8];
        o[0] = make_ushort4(v[0], v[1], v[2], v[3]);
        o[1] = make_ushort4(v[4], v[5], v[6], v[7]);
    } else if (bid < 68) {
        int t = (bid - 4) * 256 + threadIdx.x;  // 16384
        const float* W = (t < 8192) ? W2 : W3;
        u16* Wsw = (t < 8192) ? Wsw2 : Wsw3;
        int tl = t & 8191;
        int lane = tl & 63;
        int n = ((tl >> 9) << 4) + (lane & 15);
        int k0 = (((tl >> 6) & 7) << 5) + ((lane >> 4) << 3);
        u16 v[8];
#pragma unroll
        for (int j = 0; j < 8; j++) v[j] = f2b(W[(size_t)n * 256 + k0 + j]);
        ushort4* o = (ushort4*)&Wsw[(size_t)tl * 8];
        o[0] = make_ushort4(v[0], v[1], v[2], v[3]);
        o[1] = make_ushort4(v[4], v[5], v[6], v[7]);
    } else {
        int i = (bid - 68) * 256 + threadIdx.x;
        if (i < (N_GRAPHS * EMB) / 4)
            ((float4*)gbuf)[i] = make_float4(0.f, 0.f, 0.f, 0.f);
    }
}

// ---------------- fused layer 1: agg8 + MFMA GEMM (8->256) ----------------
__global__ __launch_bounds__(256) void fused_l1(const u16* __restrict__ h0,
                                                const int* __restrict__ rowptr,
                                                const int* __restrict__ csr,
                                                const u16* __restrict__ Wsw1,
                                                const float* __restrict__ bias,
                                                u16* __restrict__ Hout) {
    __shared__ __attribute__((aligned(16))) u16 lds[16][256];  // 8 KB
    const int wid = threadIdx.x >> 6;
    const int lane = threadIdx.x & 63;
    const int row0 = blockIdx.x * 16;
    char* ldsb = (char*)lds;
    const char* h0c = (const char*)h0;

    // ---- phase 1: merged gather over rows rbase..rbase+3 ----
    const int eslot = lane >> 2;       // edge slot 0..15
    const int c4 = (lane & 3) * 4;     // byte offset of lane's 2 channels
    const int rbase = row0 + wid * 4;
    int s0 = RFL(rowptr[rbase + 0]);
    int t0 = RFL(rowptr[rbase + 1]);
    int t1 = RFL(rowptr[rbase + 2]);
    int t2 = RFL(rowptr[rbase + 3]);
    int t3 = RFL(rowptr[rbase + 4]);

    f32x2 a0 = {0.f, 0.f}, a1 = {0.f, 0.f}, a2 = {0.f, 0.f}, a3 = {0.f, 0.f};
    int ee = s0;
    int ce0 = ee + eslot;
    if (ce0 > t3 - 1) ce0 = t3 - 1;
    if (ce0 < 0) ce0 = 0;
    int idxv = csr[ce0];
    while (ee < t3) {
        int ed = ee + eslot;
        unsigned v = *(const unsigned*)(h0c + (size_t)idxv * 16 + c4);
        int ce = ed + 16;
        if (ce > t3 - 1) ce = t3 - 1;
        if (ce < 0) ce = 0;
        int nidx = csr[ce];
        f32x2 u = unpk(v);
        bool b0 = ed < t0, b1 = ed < t1, b2 = ed < t2, b3 = ed < t3;
        if (b0) a0 += u;
        else if (b1) a1 += u;
        else if (b2) a2 += u;
        else if (b3) a3 += u;
        idxv = nidx;
        ee += 16;
    }
#pragma unroll
    for (int off = 4; off <= 32; off <<= 1) {
        a0[0] += __shfl_xor(a0[0], off, 64); a0[1] += __shfl_xor(a0[1], off, 64);
        a1[0] += __shfl_xor(a1[0], off, 64); a1[1] += __shfl_xor(a1[1], off, 64);
        a2[0] += __shfl_xor(a2[0], off, 64); a2[1] += __shfl_xor(a2[1], off, 64);
        a3[0] += __shfl_xor(a3[0], off, 64); a3[1] += __shfl_xor(a3[1], off, 64);
    }
    if (eslot == 0)      *(unsigned*)(ldsb + (wid * 4 + 0) * 16 + c4) = pk2(a0);
    else if (eslot == 1) *(unsigned*)(ldsb + (wid * 4 + 1) * 16 + c4) = pk2(a1);
    else if (eslot == 2) *(unsigned*)(ldsb + (wid * 4 + 2) * 16 + c4) = pk2(a2);
    else if (eslot == 3) *(unsigned*)(ldsb + (wid * 4 + 3) * 16 + c4) = pk2(a3);
    __syncthreads();

    // ---- phase 2: A fragment (K=32: k<8 real, rest zero) ----
    const int m = lane & 15;
    const int g = lane >> 4;
    bf16x8 a = {};
    if (g == 0) a = *(const bf16x8*)(ldsb + m * 16);
    __syncthreads();

    // ---- phase 3: 1 MFMA per col-tile ----
    f32x4 acc[4];
#pragma unroll
    for (int t = 0; t < 4; t++) acc[t] = (f32x4){0.f, 0.f, 0.f, 0.f};
    const bf16x8* wp = (const bf16x8*)Wsw1 + lane;
#pragma unroll
    for (int t = 0; t < 4; t++) {
        bf16x8 b = wp[(wid * 4 + t) * 64];
        acc[t] = __builtin_amdgcn_mfma_f32_16x16x32_bf16(a, b, acc[t], 0, 0, 0);
    }

    // ---- phase 4: C -> LDS (bf16, swizzled [16][512B]) ----
#pragma unroll
    for (int t = 0; t < 4; t++) {
        int col = (wid * 4 + t) * 16 + m;
#pragma unroll
        for (int r = 0; r < 4; r++) {
            int row = g * 4 + r;
            *(u16*)(ldsb + row * 512 + ((col * 2) ^ ((row & 7) << 4))) = f2b(acc[t][r]);
        }
    }
    __syncthreads();

    // ---- phase 5: epilogue relu + bias ----
    {
        int row = threadIdx.x >> 4;
        int cb0 = (threadIdx.x & 15) * 16;
#pragma unroll
        for (int p = 0; p < 2; p++) {
            int cb = cb0 + p * 256;
            ushort8 c = *(const ushort8*)(ldsb + row * 512 + (cb ^ ((row & 7) << 4)));
            int gcol = cb >> 1;
            size_t gidx = (size_t)(row0 + row) * EMB + gcol;
            float4 bq0 = *(const float4*)&bias[gcol];
            float4 bq1 = *(const float4*)&bias[gcol + 4];
            float bb[8] = {bq0.x, bq0.y, bq0.z, bq0.w, bq1.x, bq1.y, bq1.z, bq1.w};
            ushort8 o;
#pragma unroll
            for (int j = 0; j < 8; j++)
                o[j] = f2b(fmaxf(b2f(c[j]) + bb[j], 0.f));
            *(ushort8*)&Hout[gidx] = o;
        }
    }
}

// ---------------- fused GCN layer 2 (gather depth 8) ----------------
__global__ __launch_bounds__(256, 8) void fused_gcn(const u16* __restrict__ Hin,
                                                    const int* __restrict__ rowptr,
                                                    const int* __restrict__ csr,
                                                    const u16* __restrict__ Wsw,
                                                    const float* __restrict__ bias,
                                                    u16* __restrict__ Hout) {
    __shared__ __attribute__((aligned(16))) u16 lds[16][256];  // 8 KB
    const int wid = threadIdx.x >> 6;
    const int lane = threadIdx.x & 63;
    const int row0 = blockIdx.x * 16;
    char* ldsb = (char*)lds;
    const char* hbase = (const char*)Hin;
    const int laneByte = lane * 8;

    const int rbase = row0 + wid * 4;
    int s0 = RFL(rowptr[rbase + 0]);
    int t0 = RFL(rowptr[rbase + 1]);
    int t1 = RFL(rowptr[rbase + 2]);
    int t2 = RFL(rowptr[rbase + 3]);
    int t3 = RFL(rowptr[rbase + 4]);

    f32x2 r0a = {0.f, 0.f}, r0b = {0.f, 0.f};
    f32x2 r1a = {0.f, 0.f}, r1b = {0.f, 0.f};
    f32x2 r2a = {0.f, 0.f}, r2b = {0.f, 0.f};
    f32x2 r3a = {0.f, 0.f}, r3b = {0.f, 0.f};

    int idx[8];
#pragma unroll
    for (int d = 0; d < 8; d++) {
        int ce = s0 + d;
        if (ce > t3 - 1) ce = t3 - 1;
        if (ce < 0) ce = 0;
        idx[d] = RFL(csr[ce]);
    }
    int ee = s0;
    while (ee < t3) {
        uint2 v[8];
#pragma unroll
        for (int d = 0; d < 8; d++)
            v[d] = *(const uint2*)(hbase + (size_t)idx[d] * (EMB * 2) + laneByte);
        int eb = ee;
        ee += 8;
#pragma unroll
        for (int d = 0; d < 8; d++) {
            int ce = ee + d;
            if (ce > t3 - 1) ce = t3 - 1;
            if (ce < 0) ce = 0;
            idx[d] = RFL(csr[ce]);
        }
#pragma unroll
        for (int d = 0; d < 8; d++) {
            int ed = eb + d;
            if (ed < t3) {  // wave-uniform
                f32x2 ux = unpk(v[d].x), uy = unpk(v[d].y);
                if (ed < t0)      { r0a += ux; r0b += uy; }
                else if (ed < t1) { r1a += ux; r1b += uy; }
                else if (ed < t2) { r2a += ux; r2b += uy; }
                else              { r3a += ux; r3b += uy; }
            }
        }
    }

    {
        f32x2 lo[4] = {r0a, r1a, r2a, r3a};
        f32x2 hi[4] = {r0b, r1b, r2b, r3b};
#pragma unroll
        for (int r = 0; r < 4; r++) {
            int li = wid * 4 + r;
            *(uint2*)(ldsb + li * 512 + (laneByte ^ ((li & 7) << 4))) = make_uint2(pk2(lo[r]), pk2(hi[r]));
        }
    }
    __syncthreads();

    // ---- phase 2: A fragments ----
    const int m = lane & 15;
    const int g = lane >> 4;
    bf16x8 a[8];
#pragma unroll
    for (int ks = 0; ks < 8; ks++) {
        int boff = (g * 16 + ks * 64) ^ ((m & 7) << 4);
        a[ks] = *(const bf16x8*)(ldsb + m * 512 + boff);
    }
    __syncthreads();

    // ---- phase 3: MFMA ----
    f32x4 acc2[4];
#pragma unroll
    for (int t = 0; t < 4; t++) acc2[t] = (f32x4){0.f, 0.f, 0.f, 0.f};
    const bf16x8* wp = (const bf16x8*)Wsw + lane;
#pragma unroll
    for (int t = 0; t < 4; t++) {
        int nt = wid * 4 + t;
        bf16x8 b[8];
#pragma unroll
        for (int ks = 0; ks < 8; ks++) b[ks] = wp[(nt * 8 + ks) * 64];
#pragma unroll
        for (int ks = 0; ks < 8; ks++)
            acc2[t] = __builtin_amdgcn_mfma_f32_16x16x32_bf16(a[ks], b[ks], acc2[t], 0, 0, 0);
    }

    // ---- phase 4: C -> LDS (bf16, swizzled) ----
#pragma unroll
    for (int t = 0; t < 4; t++) {
        int col = (wid * 4 + t) * 16 + m;
#pragma unroll
        for (int r = 0; r < 4; r++) {
            int row = g * 4 + r;
            *(u16*)(ldsb + row * 512 + ((col * 2) ^ ((row & 7) << 4))) = f2b(acc2[t][r]);
        }
    }
    __syncthreads();

    // ---- phase 5: epilogue relu + bias + residual ----
    {
        int row = threadIdx.x >> 4;
        int cb0 = (threadIdx.x & 15) * 16;
#pragma unroll
        for (int p = 0; p < 2; p++) {
            int cb = cb0 + p * 256;
            ushort8 c = *(const ushort8*)(ldsb + row * 512 + (cb ^ ((row & 7) << 4)));
            int gcol = cb >> 1;
            size_t gidx = (size_t)(row0 + row) * EMB + gcol;
            ushort8 hres = *(const ushort8*)&Hin[gidx];
            float4 bq0 = *(const float4*)&bias[gcol];
            float4 bq1 = *(const float4*)&bias[gcol + 4];
            float bb[8] = {bq0.x, bq0.y, bq0.z, bq0.w, bq1.x, bq1.y, bq1.z, bq1.w};
            ushort8 o;
#pragma unroll
            for (int j = 0; j < 8; j++)
                o[j] = f2b(fmaxf(b2f(c[j]) + bb[j], 0.f) + b2f(hres[j]));
            *(ushort8*)&Hout[gidx] = o;
        }
    }
}

// ---------------- fused GCN layer 3 + pooling (gather depth 8) ----------------
__global__ __launch_bounds__(256, 8) void fused_gcn_pool(const u16* __restrict__ Hin,
                                                         const int* __restrict__ rowptr,
                                                         const int* __restrict__ csr,
                                                         const u16* __restrict__ Wsw,
                                                         const float* __restrict__ bias,
                                                         const int* __restrict__ seg,
                                                         float* __restrict__ g) {
    __shared__ __attribute__((aligned(16))) u16 lds[16][256];  // 8 KB
    __shared__ int segs[16];
    const int wid = threadIdx.x >> 6;
    const int lane = threadIdx.x & 63;
    const int row0 = blockIdx.x * 16;
    char* ldsb = (char*)lds;
    const char* hbase = (const char*)Hin;
    const int laneByte = lane * 8;

    const int rbase = row0 + wid * 4;
    int s0 = RFL(rowptr[rbase + 0]);
    int t0 = RFL(rowptr[rbase + 1]);
    int t1 = RFL(rowptr[rbase + 2]);
    int t2 = RFL(rowptr[rbase + 3]);
    int t3 = RFL(rowptr[rbase + 4]);

    f32x2 r0a = {0.f, 0.f}, r0b = {0.f, 0.f};
    f32x2 r1a = {0.f, 0.f}, r1b = {0.f, 0.f};
    f32x2 r2a = {0.f, 0.f}, r2b = {0.f, 0.f};
    f32x2 r3a = {0.f, 0.f}, r3b = {0.f, 0.f};

    int idx[8];
#pragma unroll
    for (int d = 0; d < 8; d++) {
        int ce = s0 + d;
        if (ce > t3 - 1) ce = t3 - 1;
        if (ce < 0) ce = 0;
        idx[d] = RFL(csr[ce]);
    }
    int ee = s0;
    while (ee < t3) {
        uint2 v[8];
#pragma unroll
        for (int d = 0; d < 8; d++)
            v[d] = *(const uint2*)(hbase + (size_t)idx[d] * (EMB * 2) + laneByte);
        int eb = ee;
        ee += 8;
#pragma unroll
        for (int d = 0; d < 8; d++) {
            int ce = ee + d;
            if (ce > t3 - 1) ce = t3 - 1;
            if (ce < 0) ce = 0;
            idx[d] = RFL(csr[ce]);
        }
#pragma unroll
        for (int d = 0; d < 8; d++) {
            int ed = eb + d;
            if (ed < t3) {
                f32x2 ux = unpk(v[d].x), uy = unpk(v[d].y);
                if (ed < t0)      { r0a += ux; r0b += uy; }
                else if (ed < t1) { r1a += ux; r1b += uy; }
                else if (ed < t2) { r2a += ux; r2b += uy; }
                else              { r3a += ux; r3b += uy; }
            }
        }
    }

    {
        f32x2 lo[4] = {r0a, r1a, r2a, r3a};
        f32x2 hi[4] = {r0b, r1b, r2b, r3b};
#pragma unroll
        for (int r = 0; r < 4; r++) {
            int li = wid * 4 + r;
            *(uint2*)(ldsb + li * 512 + (laneByte ^ ((li & 7) << 4))) = make_uint2(pk2(lo[r]), pk2(hi[r]));
        }
    }
    if (threadIdx.x < 16) segs[threadIdx.x] = seg[row0 + threadIdx.x];
    __syncthreads();

    // ---- phase 2: A fragments ----
    const int m = lane & 15;
    const int g_ = lane >> 4;
    bf16x8 a[8];
#pragma unroll
    for (int ks = 0; ks < 8; ks++) {
        int boff = (g_ * 16 + ks * 64) ^ ((m & 7) << 4);
        a[ks] = *(const bf16x8*)(ldsb + m * 512 + boff);
    }
    __syncthreads();

    // ---- phase 3: MFMA ----
    f32x4 acc2[4];
#pragma unroll
    for (int t = 0; t < 4; t++) acc2[t] = (f32x4){0.f, 0.f, 0.f, 0.f};
    const bf16x8* wp = (const bf16x8*)Wsw + lane;
#pragma unroll
    for (int t = 0; t < 4; t++) {
        int nt = wid * 4 + t;
        bf16x8 b[8];
#pragma unroll
        for (int ks = 0; ks < 8; ks++) b[ks] = wp[(nt * 8 + ks) * 64];
#pragma unroll
        for (int ks = 0; ks < 8; ks++)
            acc2[t] = __builtin_amdgcn_mfma_f32_16x16x32_bf16(a[ks], b[ks], acc2[t], 0, 0, 0);
    }

    // ---- phase 4: C -> LDS (bf16, swizzled) ----
#pragma unroll
    for (int t = 0; t < 4; t++) {
        int col = (wid * 4 + t) * 16 + m;
#pragma unroll
        for (int r = 0; r < 4; r++) {
            int row = g_ * 4 + r;
            *(u16*)(ldsb + row * 512 + ((col * 2) ^ ((row & 7) << 4))) = f2b(acc2[t][r]);
        }
    }
    __syncthreads();

    // ---- phase 5: final values (relu+bias+residual) back into LDS ----
    {
        int row = threadIdx.x >> 4;
        int cb0 = (threadIdx.x & 15) * 16;
#pragma unroll
        for (int p = 0; p < 2; p++) {
            int cb = cb0 + p * 256;
            char* lp = ldsb + row * 512 + (cb ^ ((row & 7) << 4));
            ushort8 c = *(const ushort8*)lp;
            int gcol = cb >> 1;
            size_t gidx = (size_t)(row0 + row) * EMB + gcol;
            ushort8 hres = *(const ushort8*)&Hin[gidx];
            float4 bq0 = *(const float4*)&bias[gcol];
            float4 bq1 = *(const float4*)&bias[gcol + 4];
            float bb[8] = {bq0.x, bq0.y, bq0.z, bq0.w, bq1.x, bq1.y, bq1.z, bq1.w};
            ushort8 o;
#pragma unroll
            for (int j = 0; j < 8; j++)
                o[j] = f2b(fmaxf(b2f(c[j]) + bb[j], 0.f) + b2f(hres[j]));
            *(ushort8*)lp = o;
        }
    }
    __syncthreads();

    // ---- phase 6: segment-sum the 16 rows into g (thread = channel) ----
    {
        int ch = threadIdx.x;
        float acc = 0.f;
        int gprev = segs[0];
#pragma unroll
        for (int r = 0; r < 16; r++) {
            int gr = segs[r];  // block-uniform
            float v = b2f(*(const u16*)(ldsb + r * 512 + ((ch * 2) ^ ((r & 7) << 4))));
            if (gr != gprev) {
                atomicAdd(&g[(size_t)gprev * EMB + ch], acc);
                acc = 0.f;
                gprev = gr;
            }
            acc += v;
        }
        atomicAdd(&g[(size_t)gprev * EMB + ch], acc);
    }
}

// ---------------- head: 8 graphs per block (Wp1 read shared 8x) ----------------
__global__ __launch_bounds__(256) void head8(const float* __restrict__ g, const float* __restrict__ Wp1,
                                             const float* __restrict__ Wp2, const float* __restrict__ bp2,
                                             float* __restrict__ out) {
    __shared__ float gsm[8][EMB];
    __shared__ float red[8][HID];
    int b0 = blockIdx.x * 8;
    int t = threadIdx.x;
#pragma unroll
    for (int i = 0; i < 8; i += 2) {
        // 256 threads load 2 graph vectors (512 floats) per step
        int gi = i + (t >> 7);
        int ch = (t & 127) * 2;
        float2 v = *(const float2*)&g[(size_t)(b0 + gi) * EMB + ch];
        gsm[gi][ch] = v.x; gsm[gi][ch + 1] = v.y;
    }
    __syncthreads();
    int wid = t >> 6, lane = t & 63;
    int row = wid * 32 + (lane & 31);  // 0..127
    int half = lane >> 5;
    const float* wr = &Wp1[(size_t)row * EMB + half * 128];
    float d[8];
#pragma unroll
    for (int i = 0; i < 8; i++) d[i] = 0.f;
#pragma unroll 4
    for (int k = 0; k < 128; k++) {
        float w = wr[k];
#pragma unroll
        for (int i = 0; i < 8; i++) d[i] += w * gsm[i][half * 128 + k];
    }
#pragma unroll
    for (int i = 0; i < 8; i++) d[i] += __shfl_xor(d[i], 32, 64);
    if (half == 0) {
        float w2 = Wp2[row];
#pragma unroll
        for (int i = 0; i < 8; i++) red[i][row] = fmaxf(d[i], 0.f) * w2;
    }
    __syncthreads();
    // reduce 8 x 128: group gi = t>>5 (32 threads each; 32-aligned within wave)
    int gi = t >> 5, j = t & 31;
    float s = red[gi][j] + red[gi][j + 32] + red[gi][j + 64] + red[gi][j + 96];
#pragma unroll
    for (int off = 16; off > 0; off >>= 1) s += __shfl_xor(s, off, 64);
    if (j == 0) out[b0 + gi] = s + bp2[0];
}

// ---------------- launch ----------------

extern "C" void kernel_launch(void* const* d_in, const int* in_sizes, int n_in,
                              void* d_out, int out_size, void* d_ws, size_t ws_size,
                              hipStream_t stream) {
    const float* x    = (const float*)d_in[0];
    const int*   src  = (const int*)d_in[1];
    const int*   dst  = (const int*)d_in[2];
    const int*   seg  = (const int*)d_in[3];
    const float* W_emb= (const float*)d_in[4];
    const float* W1   = (const float*)d_in[5];
    const float* b1   = (const float*)d_in[6];
    const float* W2   = (const float*)d_in[7];
    const float* b2   = (const float*)d_in[8];
    const float* W3   = (const float*)d_in[9];
    const float* b3   = (const float*)d_in[10];
    const float* Wp1  = (const float*)d_in[11];
    const float* Wp2  = (const float*)d_in[12];
    const float* bp2  = (const float*)d_in[13];
    float* out = (float*)d_out;

    char* ws = (char*)d_ws;
    size_t off = 0;
    auto alloc = [&](size_t bytes) -> void* {
        void* p = ws + off;
        off = (off + bytes + 255) & ~(size_t)255;
        return p;
    };
    const int N = N_NODES, E = N_EDGES, G = N_GRAPHS;
    u16* hA     = (u16*)alloc((size_t)N * EMB * 2);
    u16* hB     = (u16*)alloc((size_t)N * EMB * 2);
    u16* h0     = (u16*)alloc((size_t)N * IN_CH * 2);
    u16* Wsw1   = (u16*)alloc(16 * 64 * 8 * 2);
    u16* Wsw2   = (u16*)alloc(256 * 256 * 2);
    u16* Wsw3   = (u16*)alloc(256 * 256 * 2);
    int* rowptr = (int*)alloc((size_t)(N + 1) * 4);
    int* deg    = (int*)alloc((size_t)N * 4);
    int* csr    = (int*)alloc((size_t)E * 4);
    int* partials = (int*)alloc(1024 * 4);
    float* gbuf = (float*)alloc((size_t)G * EMB * 4);

    if (off > ws_size) return;  // clean failure instead of OOB crash

    // CSR build + layer-1 prep, with independent work merged per launch
    hipMemsetAsync(deg, 0, (size_t)N * 4, stream);
    emb_count<<<782 + 3125, 256, 0, stream>>>(x, W_emb, h0, dst, deg);   // emb8 || count_deg
    scan_a<<<196, 256, 0, stream>>>(deg, rowptr + 1, partials, N);
    scan_bc<<<782, 256, 0, stream>>>(rowptr, partials, N);               // scan_b+scan_c merged
    fill_prep<<<3125 + 1068, 256, 0, stream>>>(src, dst, rowptr, deg, csr,
                                               W1, W2, W3, Wsw1, Wsw2, Wsw3, gbuf);  // fill_csr || prep

    // layer 1: hA = relu(agg(h0) @ W1.T + b1)
    fused_l1<<<N / 16, 256, 0, stream>>>(h0, rowptr, csr, Wsw1, b1, hA);
    // layer 2: hB = relu(agg(hA) @ W2.T + b2) + hA
    fused_gcn<<<N / 16, 256, 0, stream>>>(hA, rowptr, csr, Wsw2, b2, hB);
    // layer 3 + pooling: g += segsum( relu(agg(hB) @ W3.T + b3) + hB )
    fused_gcn_pool<<<N / 16, 256, 0, stream>>>(hB, rowptr, csr, Wsw3, b3, seg, gbuf);

    // head
    head8<<<G / 8, 256, 0, stream>>>(gbuf, Wp1, Wp2, bp2, out);
}